// Round 1
// baseline (1859.226 us; speedup 1.0000x reference)
//
#include <hip/hip_runtime.h>

#define TT 18

static __device__ __forceinline__ float frcp(float x) { return __builtin_amdgcn_rcpf(x); }

// ---------------------------------------------------------------------------
// Head precompute: B[r][k][t][jg] (24*2*18*128) and C[r][k] (48) into d_ws.
// out[b,r,k] = sum_{t,jg} hcat[t,jg] * B[r,k,t,jg] + C[r,k]
// where B[r,k,t,jg] = sum_{c: 0<=t*24+c-r*18<18} fc2_w[k, t*24+c-r*18] * fc1_w[c, jg]
//       C[r,k]      = fc2_b[k] + sum_s fc2_w[k,s] * fc1_b[(r*18+s)%24]
// ---------------------------------------------------------------------------
__global__ __launch_bounds__(256) void head_precompute(
    const float* __restrict__ fc1_w, const float* __restrict__ fc1_b,
    const float* __restrict__ fc2_w, const float* __restrict__ fc2_b,
    float* __restrict__ Bmat, float* __restrict__ Cvec)
{
    int idx = blockIdx.x * 256 + threadIdx.x;
    if (idx < 24 * 2 * 18 * 128) {
        int jg = idx & 127;
        int t  = (idx >> 7) % 18;
        int k  = (idx / 2304) & 1;   // 2304 = 18*128
        int r  = idx / 4608;         // 4608 = 2*18*128
        float acc = 0.f;
        for (int c = 0; c < 24; ++c) {
            int s = t * 24 + c - r * 18;
            if (s >= 0 && s < 18) acc += fc2_w[k * 18 + s] * fc1_w[c * 128 + jg];
        }
        Bmat[idx] = acc;
    }
    if (idx < 48) {
        int k = idx & 1, r = idx >> 1;
        float acc = fc2_b[k];
        for (int s = 0; s < 18; ++s)
            acc += fc2_w[k * 18 + s] * fc1_b[(r * 18 + s) % 24];
        Cvec[idx] = acc;
    }
}

// ---------------------------------------------------------------------------
// Fused bidirectional GRU + head.
// Block: 256 threads = 4 waves over 64 batch elements.
//   wave 0: dir=0 (fwd), j in [0,32)    wave 1: dir=0, j in [32,64)
//   wave 2: dir=1 (bwd), j in [0,32)    wave 3: dir=1, j in [32,64)
// lane = local batch index. h exchanged via double-buffered LDS each step.
// Weights are wave-uniform -> scalar loads + SGPR-operand FMAs.
// ---------------------------------------------------------------------------
__global__ __launch_bounds__(256, 2) void gru_fused(
    const float* __restrict__ x,
    const float* __restrict__ w_ih_f, const float* __restrict__ w_hh_f,
    const float* __restrict__ b_ih_f, const float* __restrict__ b_hh_f,
    const float* __restrict__ w_ih_b, const float* __restrict__ w_hh_b,
    const float* __restrict__ b_ih_b, const float* __restrict__ b_hh_b,
    const float* __restrict__ Bmat, const float* __restrict__ Cvec,
    float* __restrict__ out)
{
    __shared__ float lds[16384];   // 64 KiB: [parity][dir][j(64)][lane(64)]; reused for combine
    const int tid  = threadIdx.x;
    const int lane = tid & 63;
    const int wave = tid >> 6;
    const int dir  = wave >> 1;
    const int half = wave & 1;
    const int b    = blockIdx.x * 64 + lane;
    const int jg0  = wave * 32;    // = dir*64 + half*32, slice into the concat dim

    const float* __restrict__ w_ih = dir ? w_ih_b : w_ih_f;
    const float* __restrict__ w_hh = dir ? w_hh_b : w_hh_f;
    const float* __restrict__ b_ih = dir ? b_ih_b : b_ih_f;
    const float* __restrict__ b_hh = dir ? b_hh_b : b_hh_f;

    float h[64];
    #pragma unroll
    for (int k = 0; k < 64; ++k) h[k] = 0.f;

    // acc[slot = 2t+ri][k]; slot is compile-time (t-loop fully unrolled).
    float acc0[36], acc1[36];
    #pragma unroll
    for (int s = 0; s < 36; ++s) { acc0[s] = 0.f; acc1[s] = 0.f; }

    // rows r active at aligned time t are {R0[t], R0[t]+1}; R0[t] = 4*(t/3)+t%3
    static constexpr int R0[18] = {0,1,2,4,5,6,8,9,10,12,13,14,16,17,18,20,21,22};

    #pragma unroll
    for (int t = 0; t < TT; ++t) {
        const int p  = t & 1;          // write parity this step
        const int pr = (t - 1) & 1;    // read parity (valid for t>0)
        if (t > 0) {
            #pragma unroll
            for (int k = 0; k < 64; ++k)
                h[k] = lds[((pr * 2 + dir) * 64 + k) * 64 + lane];
        }
        const int tx = dir ? (TT - 1 - t) : t;       // time index into x / aligned time
        const float2 xv = *(const float2*)(x + b * 36 + tx * 2);
        const int r0s = dir ? R0[TT - 1 - t] : R0[t];
        const int base0 = ((r0s * 2 + 0) * 18 + tx) * 128 + jg0;

        #pragma unroll 1
        for (int j0 = 0; j0 < 32; ++j0) {
            const int g = half * 32 + j0;
            const float* wr = w_hh + g * 64;
            float gr = b_hh[g];
            float gz = b_hh[64 + g];
            float gn = b_hh[128 + g];
            #pragma unroll
            for (int k = 0; k < 64; ++k) {
                gr = fmaf(h[k], wr[k],        gr);
                gz = fmaf(h[k], wr[k + 4096], gz);
                gn = fmaf(h[k], wr[k + 8192], gn);
            }
            float xr = fmaf(w_ih[2*g+1],         xv.y, fmaf(w_ih[2*g],         xv.x, b_ih[g]));
            float xz = fmaf(w_ih[2*(64+g)+1],    xv.y, fmaf(w_ih[2*(64+g)],    xv.x, b_ih[64+g]));
            float xn = fmaf(w_ih[2*(128+g)+1],   xv.y, fmaf(w_ih[2*(128+g)],   xv.x, b_ih[128+g]));

            float r = frcp(1.f + __expf(-(xr + gr)));
            float z = frcp(1.f + __expf(-(xz + gz)));
            float a = fmaf(r, gn, xn);
            float n = fmaf(2.f, frcp(1.f + __expf(-2.f * a)), -1.f);   // tanh(a)
            float hold = (t == 0) ? 0.f : lds[((pr * 2 + dir) * 64 + g) * 64 + lane];
            float hnew = fmaf(z, hold - n, n);                          // (1-z)*n + z*h

            // fused head: 2 active rows x 2 outputs, uniform B scalar loads
            acc0[2*t]     = fmaf(hnew, Bmat[base0        + j0], acc0[2*t]);
            acc1[2*t]     = fmaf(hnew, Bmat[base0 + 2304 + j0], acc1[2*t]);
            acc0[2*t + 1] = fmaf(hnew, Bmat[base0 + 4608 + j0], acc0[2*t + 1]);
            acc1[2*t + 1] = fmaf(hnew, Bmat[base0 + 6912 + j0], acc1[2*t + 1]);

            lds[((p * 2 + dir) * 64 + g) * 64 + lane] = hnew;
        }
        __syncthreads();
    }

    // --- combine: per-wave region lds[wave*3072 + lane*48 + (r*2+k)] ---
    {
        const int base = wave * 3072 + lane * 48;
        #pragma unroll
        for (int i = 0; i < 48; ++i) lds[base + i] = 0.f;
        #pragma unroll
        for (int s = 0; s < 36; ++s) {
            int t  = s >> 1, ri = s & 1;
            int ta = dir ? (TT - 1 - t) : t;
            int r  = 4 * (ta / 3) + ta % 3 + ri;
            lds[base + 2 * r]     += acc0[s];
            lds[base + 2 * r + 1] += acc1[s];
        }
    }
    __syncthreads();

    #pragma unroll
    for (int rep = 0; rep < 12; ++rep) {
        int o = rep * 256 + tid;   // enumerates (b_local, r, k) row-major: 64*48 = 3072
        float v = lds[o] + lds[3072 + o] + lds[6144 + o] + lds[9216 + o] + Cvec[o % 48];
        out[(size_t)blockIdx.x * 3072 + o] = v;
    }
}

extern "C" void kernel_launch(void* const* d_in, const int* in_sizes, int n_in,
                              void* d_out, int out_size, void* d_ws, size_t ws_size,
                              hipStream_t stream) {
    const float* x      = (const float*)d_in[0];
    const float* w_ih_f = (const float*)d_in[1];
    const float* w_hh_f = (const float*)d_in[2];
    const float* b_ih_f = (const float*)d_in[3];
    const float* b_hh_f = (const float*)d_in[4];
    const float* w_ih_b = (const float*)d_in[5];
    const float* w_hh_b = (const float*)d_in[6];
    const float* b_ih_b = (const float*)d_in[7];
    const float* b_hh_b = (const float*)d_in[8];
    const float* fc1_w  = (const float*)d_in[9];
    const float* fc1_b  = (const float*)d_in[10];
    const float* fc2_w  = (const float*)d_in[11];
    const float* fc2_b  = (const float*)d_in[12];
    float* out  = (float*)d_out;
    float* Bmat = (float*)d_ws;            // 110592 floats
    float* Cvec = Bmat + 110592;           // 48 floats

    head_precompute<<<432, 256, 0, stream>>>(fc1_w, fc1_b, fc2_w, fc2_b, Bmat, Cvec);
    gru_fused<<<512, 256, 0, stream>>>(x, w_ih_f, w_hh_f, b_ih_f, b_hh_f,
                                       w_ih_b, w_hh_b, b_ih_b, b_hh_b,
                                       Bmat, Cvec, out);
}

// Round 2
// 303.889 us; speedup vs baseline: 6.1181x; 6.1181x over previous
//
#include <hip/hip_runtime.h>

#define TT 18

typedef __attribute__((ext_vector_type(8))) short short8;     // 8 bf16 = 4 VGPRs
typedef __attribute__((ext_vector_type(4))) float float4_t;   // MFMA accumulator

static __device__ __forceinline__ float frcp(float x){ return __builtin_amdgcn_rcpf(x); }
static __device__ __forceinline__ float sigm(float x){ return frcp(1.f + __expf(-x)); }
static __device__ __forceinline__ float tanh_fast(float x){ return fmaf(2.f, frcp(1.f + __expf(-2.f*x)), -1.f); }
static __device__ __forceinline__ float bf16_hi_f(float f){
    return __uint_as_float(__float_as_uint(f) & 0xffff0000u);
}

// ---------------------------------------------------------------------------
// Head precompute (verified round 1): Bmat[(2r+k)*18+ta][128], Cvec[48] in ws.
// out[b,r,k] = sum_{ta,jg} hcat[ta,jg]*Bmat[...] + Cvec[2r+k]
// ---------------------------------------------------------------------------
__global__ __launch_bounds__(256) void head_precompute(
    const float* __restrict__ fc1_w, const float* __restrict__ fc1_b,
    const float* __restrict__ fc2_w, const float* __restrict__ fc2_b,
    float* __restrict__ Bmat, float* __restrict__ Cvec)
{
    int idx = blockIdx.x * 256 + threadIdx.x;
    if (idx < 24 * 2 * 18 * 128) {
        int jg = idx & 127;
        int t  = (idx >> 7) % 18;
        int k  = (idx / 2304) & 1;
        int r  = idx / 4608;
        float acc = 0.f;
        for (int c = 0; c < 24; ++c) {
            int s = t * 24 + c - r * 18;
            if (s >= 0 && s < 18) acc += fc2_w[k * 18 + s] * fc1_w[c * 128 + jg];
        }
        Bmat[idx] = acc;
    }
    if (idx < 48) {
        int k = idx & 1, r = idx >> 1;
        float acc = fc2_b[k];
        for (int s = 0; s < 18; ++s)
            acc += fc2_w[k * 18 + s] * fc1_b[(r * 18 + s) % 24];
        Cvec[idx] = acc;
    }
}

// ---------------------------------------------------------------------------
// MFMA GRU: block = 256 threads (4 waves), 16 batches, both dirs.
// wave w: dir = w>>1, nh = w&1 (gate-half). Wave computes the 16x192 gate
// GEMM slice for its dir via split-bf16 MFMA (3 terms), weights persistent
// in VGPR B-fragments. h round-trips LDS (C-layout -> A-layout).
// Head accumulated into LDS out_acc with exclusive per-step cell ownership.
// ---------------------------------------------------------------------------
struct SM {
    alignas(16) unsigned short h_hi[2][16][72];  // [dir][b][j], stride 72 (144B, 16B-aligned)
    alignas(16) unsigned short h_lo[2][16][72];
    float h_f32[2][16][65];                      // for head reads (stride 65: conflict-free)
    float x_s[16][36];                           // staged x for block's batches
    float out_acc[16][48];                       // fused head accumulator
};

static __device__ __forceinline__ void head_step(SM& sm, const float* __restrict__ Bmat,
                                                 int s, int tid)
{
    // tid < 128: b = tid&15, dir = (tid>>4)&1, i = tid>>5 in [0,4)
    int b = tid & 15;
    int d = (tid >> 4) & 1;
    int i = tid >> 5;
    int ta = d ? (TT - 1 - s) : s;               // aligned time of hidden state s
    int r  = 4 * (ta / 3) + ta % 3 + (i >> 1);   // R0[ta] + row offset
    int k  = i & 1;
    const float* bp = Bmat + ((r * 2 + k) * TT + ta) * 128 + d * 64;
    const float* hp = sm.h_f32[d][b];
    float p = 0.f;
    #pragma unroll
    for (int j = 0; j < 64; ++j) p = fmaf(hp[j], bp[j], p);
    sm.out_acc[b][r * 2 + k] += p;               // exclusive owner within this step
}

__global__ __launch_bounds__(256, 2) void gru_mfma(
    const float* __restrict__ x,
    const float* __restrict__ w_ih_f, const float* __restrict__ w_hh_f,
    const float* __restrict__ b_ih_f, const float* __restrict__ b_hh_f,
    const float* __restrict__ w_ih_b, const float* __restrict__ w_hh_b,
    const float* __restrict__ b_ih_b, const float* __restrict__ b_hh_b,
    const float* __restrict__ Bmat, const float* __restrict__ Cvec,
    float* __restrict__ out)
{
    __shared__ SM sm;
    const int tid  = threadIdx.x;
    const int lane = tid & 63;
    const int wave = tid >> 6;
    const int dir  = wave >> 1;
    const int nh   = wave & 1;
    const int col  = lane & 15;     // N-index within tile / A's m-index
    const int quad = lane >> 4;     // k-chunk selector in A/B frags; row group in C
    const int bb   = blockIdx.x * 16;

    const float* __restrict__ wih = dir ? w_ih_b : w_ih_f;
    const float* __restrict__ whh = dir ? w_hh_b : w_hh_f;
    const float* __restrict__ bih = dir ? b_ih_b : b_ih_f;
    const float* __restrict__ bhh = dir ? b_hh_b : b_hh_f;

    // ---- stage x, zero LDS ----
    for (int o = tid; o < 16 * 36; o += 256)
        ((float*)sm.x_s)[o] = x[(size_t)bb * 36 + o];
    for (int o = tid; o < 2 * 16 * 72; o += 256) {
        ((unsigned short*)sm.h_hi)[o] = 0;
        ((unsigned short*)sm.h_lo)[o] = 0;
    }
    for (int o = tid; o < 16 * 48; o += 256)
        ((float*)sm.out_acc)[o] = 0.f;

    // ---- persistent B-fragments: W split into bf16 hi/lo, B-frag layout ----
    // frag index f = type*2 + jtl; gate g = type*64 + (2*nh+jtl)*16 + col
    // B[n=col][k = quad*8 + e + c*32] = whh[g*64 + k]
    short8 bfh[6][2], bfl[6][2];
    #pragma unroll
    for (int type = 0; type < 3; ++type)
      #pragma unroll
      for (int jtl = 0; jtl < 2; ++jtl) {
        int g = type * 64 + (2 * nh + jtl) * 16 + col;
        #pragma unroll
        for (int c = 0; c < 2; ++c) {
            const float* p = whh + g * 64 + c * 32 + quad * 8;
            float4_t f0 = *(const float4_t*)(p);
            float4_t f1 = *(const float4_t*)(p + 4);
            short8 hi, lo;
            #pragma unroll
            for (int e = 0; e < 8; ++e) {
                float f  = (e < 4) ? f0[e] : f1[e - 4];
                float fh = bf16_hi_f(f);
                hi[e] = (short)(__float_as_uint(f) >> 16);
                lo[e] = (short)(__float_as_uint(f - fh) >> 16);
            }
            bfh[type * 2 + jtl][c] = hi;
            bfl[type * 2 + jtl][c] = lo;
        }
      }

    // ---- per-lane elementwise constants ----
    float wc0[2][3], wc1[2][3], bc[2][3], bhn[2];
    #pragma unroll
    for (int jtl = 0; jtl < 2; ++jtl)
      #pragma unroll
      for (int type = 0; type < 3; ++type) {
        int g = type * 64 + (2 * nh + jtl) * 16 + col;
        wc0[jtl][type] = wih[2 * g];
        wc1[jtl][type] = wih[2 * g + 1];
        bc[jtl][type]  = (type < 2) ? (bih[g] + bhh[g]) : bih[g];
        if (type == 2) bhn[jtl] = bhh[g];
      }

    float hprev[2][4] = {{0.f,0.f,0.f,0.f},{0.f,0.f,0.f,0.f}};  // [jtl][reg]

    __syncthreads();

    #pragma unroll 1
    for (int t = 0; t < TT; ++t) {
        // (A) fused head for the hidden states produced at step t-1
        if (t > 0 && tid < 128) head_step(sm, Bmat, t - 1, tid);

        // (B) A-fragments from LDS (h of step t-1; zeros at t=0)
        short8 afh[2], afl[2];
        #pragma unroll
        for (int c = 0; c < 2; ++c) {
            afh[c] = *(const short8*)&sm.h_hi[dir][col][c * 32 + quad * 8];
            afl[c] = *(const short8*)&sm.h_lo[dir][col][c * 32 + quad * 8];
        }
        __syncthreads();   // all reads of step t-1 data complete

        // (C) split-fp32 MFMA: gh = h @ whh^T for 6 gate tiles
        float4_t acc[6];
        #pragma unroll
        for (int i = 0; i < 6; ++i) acc[i] = (float4_t){0.f, 0.f, 0.f, 0.f};
        #pragma unroll
        for (int i = 0; i < 6; ++i)
          #pragma unroll
          for (int c = 0; c < 2; ++c) {
            acc[i] = __builtin_amdgcn_mfma_f32_16x16x32_bf16(afh[c], bfh[i][c], acc[i], 0, 0, 0);
            acc[i] = __builtin_amdgcn_mfma_f32_16x16x32_bf16(afh[c], bfl[i][c], acc[i], 0, 0, 0);
            acc[i] = __builtin_amdgcn_mfma_f32_16x16x32_bf16(afl[c], bfh[i][c], acc[i], 0, 0, 0);
          }

        // (D) elementwise gates + h write-back (C-layout: b=quad*4+reg, j=tile*16+col)
        const int tx = dir ? (TT - 1 - t) : t;
        #pragma unroll
        for (int reg = 0; reg < 4; ++reg) {
            int b = quad * 4 + reg;
            float x0 = sm.x_s[b][tx * 2];
            float x1 = sm.x_s[b][tx * 2 + 1];
            #pragma unroll
            for (int jtl = 0; jtl < 2; ++jtl) {
                float gr = acc[0 + jtl][reg];
                float gz = acc[2 + jtl][reg];
                float gn = acc[4 + jtl][reg];
                float r = sigm(fmaf(wc0[jtl][0], x0, fmaf(wc1[jtl][0], x1, bc[jtl][0])) + gr);
                float z = sigm(fmaf(wc0[jtl][1], x0, fmaf(wc1[jtl][1], x1, bc[jtl][1])) + gz);
                float hn = gn + bhn[jtl];
                float a  = fmaf(r, hn, fmaf(wc0[jtl][2], x0, fmaf(wc1[jtl][2], x1, bc[jtl][2])));
                float n  = tanh_fast(a);
                float hp = hprev[jtl][reg];
                float hnew = fmaf(z, hp - n, n);
                hprev[jtl][reg] = hnew;
                int j = (2 * nh + jtl) * 16 + col;
                float fh = bf16_hi_f(hnew);
                sm.h_hi[dir][b][j]  = (unsigned short)(__float_as_uint(hnew) >> 16);
                sm.h_lo[dir][b][j]  = (unsigned short)(__float_as_uint(hnew - fh) >> 16);
                sm.h_f32[dir][b][j] = hnew;
            }
        }
        __syncthreads();   // step-t writes visible for next iteration
    }

    // head for the final step's hidden states
    if (tid < 128) head_step(sm, Bmat, TT - 1, tid);
    __syncthreads();

    // epilogue: out[bb + b][r][k] = out_acc + Cvec
    #pragma unroll
    for (int rep = 0; rep < 3; ++rep) {
        int o = rep * 256 + tid;          // 768 = 16 b * 48 cells
        int b = o / 48, c = o % 48;
        out[(size_t)bb * 48 + o] = sm.out_acc[b][c] + Cvec[c];
    }
}

extern "C" void kernel_launch(void* const* d_in, const int* in_sizes, int n_in,
                              void* d_out, int out_size, void* d_ws, size_t ws_size,
                              hipStream_t stream) {
    const float* x      = (const float*)d_in[0];
    const float* w_ih_f = (const float*)d_in[1];
    const float* w_hh_f = (const float*)d_in[2];
    const float* b_ih_f = (const float*)d_in[3];
    const float* b_hh_f = (const float*)d_in[4];
    const float* w_ih_b = (const float*)d_in[5];
    const float* w_hh_b = (const float*)d_in[6];
    const float* b_ih_b = (const float*)d_in[7];
    const float* b_hh_b = (const float*)d_in[8];
    const float* fc1_w  = (const float*)d_in[9];
    const float* fc1_b  = (const float*)d_in[10];
    const float* fc2_w  = (const float*)d_in[11];
    const float* fc2_b  = (const float*)d_in[12];
    float* out  = (float*)d_out;
    float* Bmat = (float*)d_ws;            // 110592 floats
    float* Cvec = Bmat + 110592;           // 48 floats

    head_precompute<<<432, 256, 0, stream>>>(fc1_w, fc1_b, fc2_w, fc2_b, Bmat, Cvec);
    gru_mfma<<<2048, 256, 0, stream>>>(x, w_ih_f, w_hh_f, b_ih_f, b_hh_f,
                                       w_ih_b, w_hh_b, b_ih_b, b_hh_b,
                                       Bmat, Cvec, out);
}

// Round 3
// 233.704 us; speedup vs baseline: 7.9555x; 1.3003x over previous
//
#include <hip/hip_runtime.h>

#define TT 18

typedef __attribute__((ext_vector_type(8))) short short8;     // 8 bf16 = 4 VGPRs
typedef __attribute__((ext_vector_type(4))) float float4_t;
typedef __attribute__((ext_vector_type(2))) unsigned int uint2_t;

static __device__ __forceinline__ float frcp(float x){ return __builtin_amdgcn_rcpf(x); }
static __device__ __forceinline__ float sigm(float x){ return frcp(1.f + __expf(-x)); }
static __device__ __forceinline__ float tanh_fast(float x){ return fmaf(2.f, frcp(1.f + __expf(-2.f*x)), -1.f); }

// split fp32 -> bf16 hi + bf16 lo (truncation; lo catches next 8 mantissa bits)
static __device__ __forceinline__ void split8(float4_t f0, float4_t f1, short8& hi, short8& lo){
  #pragma unroll
  for (int e = 0; e < 8; ++e){
    float f = (e < 4) ? f0[e] : f1[e-4];
    unsigned u = __float_as_uint(f);
    hi[e] = (short)(u >> 16);
    float fh = __uint_as_float(u & 0xffff0000u);
    lo[e] = (short)(__float_as_uint(f - fh) >> 16);
  }
}

// ---------------------------------------------------------------------------
// Head precompute (verified rounds 1-2): Bmat[(2r+k)*18+ta][128], Cvec[48].
// out[b,r,k] = sum_{ta,jg} hcat[ta,jg]*Bmat[...] + Cvec[2r+k]
// ---------------------------------------------------------------------------
__global__ __launch_bounds__(256) void head_precompute(
    const float* __restrict__ fc1_w, const float* __restrict__ fc1_b,
    const float* __restrict__ fc2_w, const float* __restrict__ fc2_b,
    float* __restrict__ Bmat, float* __restrict__ Cvec)
{
    int idx = blockIdx.x * 256 + threadIdx.x;
    if (idx < 24 * 2 * 18 * 128) {
        int jg = idx & 127;
        int t  = (idx >> 7) % 18;
        int k  = (idx / 2304) & 1;
        int r  = idx / 4608;
        float acc = 0.f;
        for (int c = 0; c < 24; ++c) {
            int s = t * 24 + c - r * 18;
            if (s >= 0 && s < 18) acc += fc2_w[k * 18 + s] * fc1_w[c * 128 + jg];
        }
        Bmat[idx] = acc;
    }
    if (idx < 48) {
        int k = idx & 1, r = idx >> 1;
        float acc = fc2_b[k];
        for (int s = 0; s < 18; ++s)
            acc += fc2_w[k * 18 + s] * fc1_b[(r * 18 + s) % 24];
        Cvec[idx] = acc;
    }
}

// ---------------------------------------------------------------------------
// MFMA GRU, swapped roles: A = W (M=gates), B = h (N=batch=16), K=64.
// Block: 4 waves; wave w: dir=w>>1, nh=w&1 (96-gate half).
// h double-buffered in LDS (bf16 hi/lo, B-frag order): ONE barrier per step.
// Head fused as MFMA (A = per-step Bmat frag, B = same h frag), done by nh==0
// waves, accumulated into LDS out_acc (cell ownership disjoint across dirs).
// ---------------------------------------------------------------------------
struct SM {
    // [parity][dir][hi/lo][ (j>>3)*128 + b*8 + (j&7) ]  (shorts)
    alignas(16) unsigned short hb[2][2][2][1024];   // 16 KiB
    float x_s[16][36];                              // staged x
    float out_acc[16][49];                          // padded stride 49
};

__global__ __launch_bounds__(256, 2) void gru_mfma(
    const float* __restrict__ x,
    const float* __restrict__ w_ih_f, const float* __restrict__ w_hh_f,
    const float* __restrict__ b_ih_f, const float* __restrict__ b_hh_f,
    const float* __restrict__ w_ih_b, const float* __restrict__ w_hh_b,
    const float* __restrict__ b_ih_b, const float* __restrict__ b_hh_b,
    const float* __restrict__ Bmat, const float* __restrict__ Cvec,
    float* __restrict__ out)
{
    __shared__ SM sm;
    const int tid  = threadIdx.x;
    const int lane = tid & 63;
    const int wave = tid >> 6;
    const int dir  = wave >> 1;
    const int nh   = wave & 1;
    const int col  = lane & 15;     // batch index (B/C col); gate m-row at A-load
    const int quad = lane >> 4;
    const int bb   = blockIdx.x * 16;

    const float* __restrict__ wih = dir ? w_ih_b : w_ih_f;
    const float* __restrict__ whh = dir ? w_hh_b : w_hh_f;
    const float* __restrict__ bih = dir ? b_ih_b : b_ih_f;
    const float* __restrict__ bhh = dir ? b_hh_b : b_hh_f;

    // ---- stage x (float4), zero parity-1 h buffer and out_acc ----
    if (tid < 144)
        ((float4_t*)sm.x_s)[tid] = ((const float4_t*)(x + (size_t)bb * 36))[tid];
    {
        unsigned* z = (unsigned*)&sm.hb[1][0][0][0];
        #pragma unroll
        for (int o = 0; o < 8; ++o) z[tid + o * 256] = 0u;
    }
    for (int o = tid; o < 16 * 49; o += 256) ((float*)sm.out_acc)[o] = 0.f;

    // ---- persistent W A-fragments (split bf16): tile = ty*2 + jhalf ----
    // A[m=col][k=quad*8+e+c*32] = whh[(ty*64 + nh*32 + jhalf*16 + col)*64 + k]
    short8 wfh[6][2], wfl[6][2];
    #pragma unroll
    for (int tile = 0; tile < 6; ++tile) {
        int ty = tile >> 1, jh = tile & 1;
        int g = ty * 64 + nh * 32 + jh * 16 + col;
        #pragma unroll
        for (int c = 0; c < 2; ++c) {
            const float* p = whh + g * 64 + c * 32 + quad * 8;
            split8(*(const float4_t*)p, *(const float4_t*)(p + 4), wfh[tile][c], wfl[tile][c]);
        }
    }

    // ---- per-thread elementwise constants: element e8 = jh*4+reg ----
    // thread's hidden index j = nh*32 + jh*16 + quad*4 + reg (batch = col)
    float w0c[3][8], w1c[3][8], bA[3][8], bN[8];
    #pragma unroll
    for (int jh = 0; jh < 2; ++jh)
      #pragma unroll
      for (int reg = 0; reg < 4; ++reg) {
        int e8 = jh * 4 + reg;
        int j  = nh * 32 + jh * 16 + quad * 4 + reg;
        #pragma unroll
        for (int ty = 0; ty < 3; ++ty) {
            int g = ty * 64 + j;
            w0c[ty][e8] = wih[2 * g];
            w1c[ty][e8] = wih[2 * g + 1];
            bA[ty][e8]  = (ty < 2) ? (bih[g] + bhh[g]) : bih[g];
        }
        bN[e8] = bhh[128 + j];
      }

    float hprev[8] = {0.f,0.f,0.f,0.f,0.f,0.f,0.f,0.f};

    __syncthreads();

    auto step = [&](int t, int pr, int pw, bool do_head) {
        // (1) h B-fragments of step t-1 from parity pr (conflict-free b128)
        short8 hfh[2], hfl[2];
        #pragma unroll
        for (int c = 0; c < 2; ++c) {
            hfh[c] = *(const short8*)&sm.hb[pr][dir][0][(c * 4 + quad) * 128 + col * 8];
            hfl[c] = *(const short8*)&sm.hb[pr][dir][1][(c * 4 + quad) * 128 + col * 8];
        }

        // (2) fused head for state s = t-1 (MFMA; nh==0 waves only)
        if (do_head && nh == 0) {
            int s  = t - 1;
            int ta = dir ? (TT - 1 - s) : s;
            int i  = col & 3;
            int r  = 4 * (ta / 3) + ta % 3 + (i >> 1);
            int kk = i & 1;
            const float* bp = Bmat + ((r * 2 + kk) * TT + ta) * 128 + dir * 64 + quad * 8;
            float4_t acch = (float4_t){0.f, 0.f, 0.f, 0.f};
            #pragma unroll
            for (int c = 0; c < 2; ++c) {
                short8 ahi, alo;
                split8(*(const float4_t*)(bp + c * 32), *(const float4_t*)(bp + c * 32 + 4), ahi, alo);
                acch = __builtin_amdgcn_mfma_f32_16x16x32_bf16(ahi, hfh[c], acch, 0, 0, 0);
                acch = __builtin_amdgcn_mfma_f32_16x16x32_bf16(ahi, hfl[c], acch, 0, 0, 0);
                acch = __builtin_amdgcn_mfma_f32_16x16x32_bf16(alo, hfh[c], acch, 0, 0, 0);
            }
            if (quad == 0) {   // C rows 0..3 hold i = 0..3, col = batch
                #pragma unroll
                for (int reg = 0; reg < 4; ++reg) {
                    int rr = 4 * (ta / 3) + ta % 3 + (reg >> 1);
                    sm.out_acc[col][rr * 2 + (reg & 1)] += acch[reg];
                }
            }
        }

        // (3) gate GEMM: 6 tiles x 2 chunks x 3 split terms
        float4_t acc[6];
        #pragma unroll
        for (int i6 = 0; i6 < 6; ++i6) acc[i6] = (float4_t){0.f, 0.f, 0.f, 0.f};
        #pragma unroll
        for (int i6 = 0; i6 < 6; ++i6)
          #pragma unroll
          for (int c = 0; c < 2; ++c) {
            acc[i6] = __builtin_amdgcn_mfma_f32_16x16x32_bf16(wfh[i6][c], hfh[c], acc[i6], 0, 0, 0);
            acc[i6] = __builtin_amdgcn_mfma_f32_16x16x32_bf16(wfh[i6][c], hfl[c], acc[i6], 0, 0, 0);
            acc[i6] = __builtin_amdgcn_mfma_f32_16x16x32_bf16(wfl[i6][c], hfh[c], acc[i6], 0, 0, 0);
          }

        // (4) elementwise gates; packed b64 write-back into parity pw
        const int tx = dir ? (TT - 1 - t) : t;
        float x0 = sm.x_s[col][tx * 2];
        float x1 = sm.x_s[col][tx * 2 + 1];
        #pragma unroll
        for (int jh = 0; jh < 2; ++jh) {
            unsigned uh[4], ul[4];
            #pragma unroll
            for (int reg = 0; reg < 4; ++reg) {
                int e8 = jh * 4 + reg;
                float gr = acc[0 + jh][reg];
                float gz = acc[2 + jh][reg];
                float gn = acc[4 + jh][reg];
                float r  = sigm(fmaf(w0c[0][e8], x0, fmaf(w1c[0][e8], x1, bA[0][e8])) + gr);
                float z  = sigm(fmaf(w0c[1][e8], x0, fmaf(w1c[1][e8], x1, bA[1][e8])) + gz);
                float xn = fmaf(w0c[2][e8], x0, fmaf(w1c[2][e8], x1, bA[2][e8]));
                float n  = tanh_fast(fmaf(r, gn + bN[e8], xn));
                float hnew = fmaf(z, hprev[e8] - n, n);
                hprev[e8] = hnew;
                unsigned u = __float_as_uint(hnew);
                uh[reg] = u;
                float fh = __uint_as_float(u & 0xffff0000u);
                ul[reg] = __float_as_uint(hnew - fh);
            }
            int off = (nh * 4 + jh * 2 + (quad >> 1)) * 128 + col * 8 + (quad & 1) * 4;
            uint2_t dh, dl;
            dh[0] = (uh[0] >> 16) | (uh[1] & 0xffff0000u);
            dh[1] = (uh[2] >> 16) | (uh[3] & 0xffff0000u);
            dl[0] = (ul[0] >> 16) | (ul[1] & 0xffff0000u);
            dl[1] = (ul[2] >> 16) | (ul[3] & 0xffff0000u);
            *(uint2_t*)&sm.hb[pw][dir][0][off] = dh;
            *(uint2_t*)&sm.hb[pw][dir][1][off] = dl;
        }
        __syncthreads();
    };

    #pragma unroll 1
    for (int tt = 0; tt < 9; ++tt) {
        step(2 * tt,     1, 0, tt > 0);
        step(2 * tt + 1, 0, 1, true);
    }

    // ---- final head for s = 17 (h17 in parity 1) ----
    if (nh == 0) {
        short8 hfh[2], hfl[2];
        #pragma unroll
        for (int c = 0; c < 2; ++c) {
            hfh[c] = *(const short8*)&sm.hb[1][dir][0][(c * 4 + quad) * 128 + col * 8];
            hfl[c] = *(const short8*)&sm.hb[1][dir][1][(c * 4 + quad) * 128 + col * 8];
        }
        int s  = TT - 1;
        int ta = dir ? (TT - 1 - s) : s;
        int i  = col & 3;
        int r  = 4 * (ta / 3) + ta % 3 + (i >> 1);
        int kk = i & 1;
        const float* bp = Bmat + ((r * 2 + kk) * TT + ta) * 128 + dir * 64 + quad * 8;
        float4_t acch = (float4_t){0.f, 0.f, 0.f, 0.f};
        #pragma unroll
        for (int c = 0; c < 2; ++c) {
            short8 ahi, alo;
            split8(*(const float4_t*)(bp + c * 32), *(const float4_t*)(bp + c * 32 + 4), ahi, alo);
            acch = __builtin_amdgcn_mfma_f32_16x16x32_bf16(ahi, hfh[c], acch, 0, 0, 0);
            acch = __builtin_amdgcn_mfma_f32_16x16x32_bf16(ahi, hfl[c], acch, 0, 0, 0);
            acch = __builtin_amdgcn_mfma_f32_16x16x32_bf16(alo, hfh[c], acch, 0, 0, 0);
        }
        if (quad == 0) {
            #pragma unroll
            for (int reg = 0; reg < 4; ++reg) {
                int rr = 4 * (ta / 3) + ta % 3 + (reg >> 1);
                sm.out_acc[col][rr * 2 + (reg & 1)] += acch[reg];
            }
        }
    }
    __syncthreads();

    // ---- epilogue ----
    #pragma unroll
    for (int rep = 0; rep < 3; ++rep) {
        int o = rep * 256 + tid;          // 768 = 16 b * 48 cells
        int b = o / 48, c = o % 48;
        out[(size_t)bb * 48 + o] = sm.out_acc[b][c] + Cvec[c];
    }
}

extern "C" void kernel_launch(void* const* d_in, const int* in_sizes, int n_in,
                              void* d_out, int out_size, void* d_ws, size_t ws_size,
                              hipStream_t stream) {
    const float* x      = (const float*)d_in[0];
    const float* w_ih_f = (const float*)d_in[1];
    const float* w_hh_f = (const float*)d_in[2];
    const float* b_ih_f = (const float*)d_in[3];
    const float* b_hh_f = (const float*)d_in[4];
    const float* w_ih_b = (const float*)d_in[5];
    const float* w_hh_b = (const float*)d_in[6];
    const float* b_ih_b = (const float*)d_in[7];
    const float* b_hh_b = (const float*)d_in[8];
    const float* fc1_w  = (const float*)d_in[9];
    const float* fc1_b  = (const float*)d_in[10];
    const float* fc2_w  = (const float*)d_in[11];
    const float* fc2_b  = (const float*)d_in[12];
    float* out  = (float*)d_out;
    float* Bmat = (float*)d_ws;            // 110592 floats
    float* Cvec = Bmat + 110592;           // 48 floats

    head_precompute<<<432, 256, 0, stream>>>(fc1_w, fc1_b, fc2_w, fc2_b, Bmat, Cvec);
    gru_mfma<<<2048, 256, 0, stream>>>(x, w_ih_f, w_hh_f, b_ih_f, b_hh_f,
                                       w_ih_b, w_hh_b, b_ih_b, b_hh_b,
                                       Bmat, Cvec, out);
}

// Round 4
// 215.903 us; speedup vs baseline: 8.6114x; 1.0824x over previous
//
#include <hip/hip_runtime.h>

#define TT 18

typedef __attribute__((ext_vector_type(8))) short short8;     // 8 bf16 = 4 VGPRs
typedef __attribute__((ext_vector_type(4))) float float4_t;
typedef __attribute__((ext_vector_type(2))) float float2_t;
typedef __attribute__((ext_vector_type(2))) unsigned int uint2_t;

static __device__ __forceinline__ float frcp(float x){ return __builtin_amdgcn_rcpf(x); }
static __device__ __forceinline__ float sigm(float x){ return frcp(1.f + __expf(-x)); }
static __device__ __forceinline__ float tanh_fast(float x){ return fmaf(2.f, frcp(1.f + __expf(-2.f*x)), -1.f); }
// round-to-nearest-even bf16, returned as the rounded fp32 bit pattern (low 16 garbage-free after >>16)
static __device__ __forceinline__ unsigned rne_bits(float f){
    unsigned u = __float_as_uint(f);
    return u + 0x7fffu + ((u >> 16) & 1u);
}
static __device__ __forceinline__ unsigned pack_hi16(unsigned hi_src, unsigned lo_src){
#if defined(__has_builtin)
#if __has_builtin(__builtin_amdgcn_perm)
    return __builtin_amdgcn_perm(hi_src, lo_src, 0x07060302u);  // [lo.b2,lo.b3,hi.b2,hi.b3]
#else
    return (lo_src >> 16) | (hi_src & 0xffff0000u);
#endif
#else
    return (lo_src >> 16) | (hi_src & 0xffff0000u);
#endif
}

// ---------------------------------------------------------------------------
// Head precompute: Bhi/Blo (bf16 split of Bmat[(2r+k)*18+ta][128]) + Cvec[48].
// out[b,r,k] = sum_{ta,jg} hcat[ta,jg]*Bmat[...] + Cvec[2r+k]
// ---------------------------------------------------------------------------
__global__ __launch_bounds__(256) void head_precompute(
    const float* __restrict__ fc1_w, const float* __restrict__ fc1_b,
    const float* __restrict__ fc2_w, const float* __restrict__ fc2_b,
    unsigned short* __restrict__ Bhi, unsigned short* __restrict__ Blo,
    float* __restrict__ Cvec)
{
    int idx = blockIdx.x * 256 + threadIdx.x;
    if (idx < 24 * 2 * 18 * 128) {
        int jg = idx & 127;
        int t  = (idx >> 7) % 18;
        int k  = (idx / 2304) & 1;
        int r  = idx / 4608;
        float acc = 0.f;
        for (int c = 0; c < 24; ++c) {
            int s = t * 24 + c - r * 18;
            if (s >= 0 && s < 18) acc += fc2_w[k * 18 + s] * fc1_w[c * 128 + jg];
        }
        unsigned rb = rne_bits(acc);
        Bhi[idx] = (unsigned short)(rb >> 16);
        float fh = __uint_as_float(rb & 0xffff0000u);
        Blo[idx] = (unsigned short)(__float_as_uint(acc - fh) >> 16);
    }
    if (idx < 48) {
        int k = idx & 1, r = idx >> 1;
        float acc = fc2_b[k];
        for (int s = 0; s < 18; ++s)
            acc += fc2_w[k * 18 + s] * fc1_b[(r * 18 + s) % 24];
        Cvec[idx] = acc;
    }
}

// ---------------------------------------------------------------------------
// MFMA GRU, dir-split blocks: 256 threads = 4 waves, ONE direction, 16 batches.
// wave jq in [0,4): gate column group. A = W (RNE bf16, persistent, 24 regs),
// B = h (hi+lo bf16, double-buffered LDS). 12 MFMAs/wave/step.
// Head: rotates across waves (jq == s&3), bf16 Bmat A-frags from ws, 6 MFMAs.
// Dirs combine via atomicAdd into memset-zeroed out (each adds Cvec/2).
// ---------------------------------------------------------------------------
struct SMv {
    alignas(16) unsigned short hb[2][2][1024];  // [parity][hi/lo][(j>>3)*128 + b*8 + (j&7)]
    float x_s[16][36];
    float out_acc[16][49];                      // stride 49: conflict-free RMW
};

__global__ __launch_bounds__(256, 4) void gru_mfma(
    const float* __restrict__ x,
    const float* __restrict__ w_ih_f, const float* __restrict__ w_hh_f,
    const float* __restrict__ b_ih_f, const float* __restrict__ b_hh_f,
    const float* __restrict__ w_ih_b, const float* __restrict__ w_hh_b,
    const float* __restrict__ b_ih_b, const float* __restrict__ b_hh_b,
    const unsigned short* __restrict__ Bhi, const unsigned short* __restrict__ Blo,
    const float* __restrict__ Cvec, float* __restrict__ out)
{
    __shared__ SMv sm;
    const int tid  = threadIdx.x;
    const int lane = tid & 63;
    const int jq   = tid >> 6;      // wave index = gate column group
    const int col  = lane & 15;     // batch (B/C col); gate row at A-load
    const int quad = lane >> 4;
    const int bi   = blockIdx.x;
    const int dir  = bi >> 11;
    const int bb   = (bi & 2047) * 16;

    const float* __restrict__ wih = dir ? w_ih_b : w_ih_f;
    const float* __restrict__ whh = dir ? w_hh_b : w_hh_f;
    const float* __restrict__ bih = dir ? b_ih_b : b_ih_f;
    const float* __restrict__ bhh = dir ? b_hh_b : b_hh_f;

    // ---- stage x, zero parity-1 h buffer and out_acc ----
    if (tid < 144)
        ((float4_t*)sm.x_s)[tid] = ((const float4_t*)(x + (size_t)bb * 36))[tid];
    {
        unsigned* z = (unsigned*)&sm.hb[1][0][0];
        #pragma unroll
        for (int o = 0; o < 4; ++o) z[tid + o * 256] = 0u;
    }
    for (int o = tid; o < 16 * 49; o += 256) ((float*)sm.out_acc)[o] = 0.f;

    // ---- persistent W A-fragments (single RNE bf16) ----
    // A[m=col][k=quad*8+e+c*32] = whh[(ty*64 + jq*16 + col)*64 + k]
    short8 wf[3][2];
    #pragma unroll
    for (int ty = 0; ty < 3; ++ty) {
        int g = ty * 64 + jq * 16 + col;
        #pragma unroll
        for (int c = 0; c < 2; ++c) {
            const float* p = whh + g * 64 + c * 32 + quad * 8;
            float4_t f0 = *(const float4_t*)p;
            float4_t f1 = *(const float4_t*)(p + 4);
            short8 s;
            #pragma unroll
            for (int e = 0; e < 8; ++e) {
                float f = (e < 4) ? f0[e] : f1[e - 4];
                s[e] = (short)(rne_bits(f) >> 16);
            }
            wf[ty][c] = s;
        }
    }

    // ---- per-thread elementwise constants: thread's gate j = jq*16+quad*4+reg ----
    float w0c[3][4], w1c[3][4], bA[3][4], bN[4];
    #pragma unroll
    for (int reg = 0; reg < 4; ++reg) {
        int j = jq * 16 + quad * 4 + reg;
        #pragma unroll
        for (int ty = 0; ty < 3; ++ty) {
            int g = ty * 64 + j;
            w0c[ty][reg] = wih[2 * g];
            w1c[ty][reg] = wih[2 * g + 1];
            bA[ty][reg]  = (ty < 2) ? (bih[g] + bhh[g]) : bih[g];
        }
        bN[reg] = bhh[128 + j];
    }

    float hprev[4] = {0.f, 0.f, 0.f, 0.f};

    __syncthreads();

    auto step = [&](int t, int pr, int pw) {
        // (1) h fragments of step t-1 (conflict-free b128 reads)
        short8 hfh[2], hfl[2];
        #pragma unroll
        for (int c = 0; c < 2; ++c) {
            hfh[c] = *(const short8*)&sm.hb[pr][0][(c * 4 + quad) * 128 + col * 8];
            hfl[c] = *(const short8*)&sm.hb[pr][1][(c * 4 + quad) * 128 + col * 8];
        }

        // (2) fused head for s = t-1, one wave per step (rotating)
        if (t > 0 && ((t - 1) & 3) == jq) {
            int s  = t - 1;
            int ta = dir ? (TT - 1 - s) : s;
            int i  = col & 3;
            int rr = 4 * (ta / 3) + ta % 3 + (i >> 1);
            int kk = i & 1;
            size_t boff = (size_t)((rr * 2 + kk) * TT + ta) * 128 + dir * 64 + quad * 8;
            float4_t acch = (float4_t){0.f, 0.f, 0.f, 0.f};
            #pragma unroll
            for (int c = 0; c < 2; ++c) {
                short8 ah = *(const short8*)(Bhi + boff + c * 32);
                short8 al = *(const short8*)(Blo + boff + c * 32);
                acch = __builtin_amdgcn_mfma_f32_16x16x32_bf16(ah, hfh[c], acch, 0, 0, 0);
                acch = __builtin_amdgcn_mfma_f32_16x16x32_bf16(ah, hfl[c], acch, 0, 0, 0);
                acch = __builtin_amdgcn_mfma_f32_16x16x32_bf16(al, hfh[c], acch, 0, 0, 0);
            }
            if (quad == 0) {
                #pragma unroll
                for (int reg = 0; reg < 4; ++reg) {
                    int r2 = 4 * (ta / 3) + ta % 3 + (reg >> 1);
                    sm.out_acc[col][r2 * 2 + (reg & 1)] += acch[reg];
                }
            }
        }

        // (3) gate GEMM: 3 tiles x 2 chunks x (h_hi + h_lo) = 12 MFMAs
        float4_t acc[3];
        #pragma unroll
        for (int ty = 0; ty < 3; ++ty) acc[ty] = (float4_t){0.f, 0.f, 0.f, 0.f};
        #pragma unroll
        for (int ty = 0; ty < 3; ++ty)
          #pragma unroll
          for (int c = 0; c < 2; ++c) {
            acc[ty] = __builtin_amdgcn_mfma_f32_16x16x32_bf16(wf[ty][c], hfh[c], acc[ty], 0, 0, 0);
            acc[ty] = __builtin_amdgcn_mfma_f32_16x16x32_bf16(wf[ty][c], hfl[c], acc[ty], 0, 0, 0);
          }

        // (4) elementwise gates; RNE hi + residual lo pack; b64 write to parity pw
        const int tx = dir ? (TT - 1 - t) : t;
        float2_t xv = *(const float2_t*)&sm.x_s[col][tx * 2];
        unsigned rh[4], ul[4];
        #pragma unroll
        for (int reg = 0; reg < 4; ++reg) {
            float r  = sigm(fmaf(w0c[0][reg], xv[0], fmaf(w1c[0][reg], xv[1], bA[0][reg])) + acc[0][reg]);
            float z  = sigm(fmaf(w0c[1][reg], xv[0], fmaf(w1c[1][reg], xv[1], bA[1][reg])) + acc[1][reg]);
            float xn = fmaf(w0c[2][reg], xv[0], fmaf(w1c[2][reg], xv[1], bA[2][reg]));
            float n  = tanh_fast(fmaf(r, acc[2][reg] + bN[reg], xn));
            float hnew = fmaf(z, hprev[reg] - n, n);
            hprev[reg] = hnew;
            unsigned rb = rne_bits(hnew);
            rh[reg] = rb;
            float fh = __uint_as_float(rb & 0xffff0000u);
            ul[reg] = __float_as_uint(hnew - fh);
        }
        int woff = (jq * 2 + (quad >> 1)) * 128 + col * 8 + (quad & 1) * 4;
        uint2_t dh, dl;
        dh[0] = pack_hi16(rh[1], rh[0]);
        dh[1] = pack_hi16(rh[3], rh[2]);
        dl[0] = pack_hi16(ul[1], ul[0]);
        dl[1] = pack_hi16(ul[3], ul[2]);
        *(uint2_t*)&sm.hb[pw][0][woff] = dh;
        *(uint2_t*)&sm.hb[pw][1][woff] = dl;
        __syncthreads();
    };

    #pragma unroll 1
    for (int tt = 0; tt < 9; ++tt) {
        step(2 * tt,     1, 0);
        step(2 * tt + 1, 0, 1);
    }

    // ---- final head for s = 17 (parity 1), wave jq == 1 ----
    if (jq == (17 & 3)) {
        short8 hfh[2], hfl[2];
        #pragma unroll
        for (int c = 0; c < 2; ++c) {
            hfh[c] = *(const short8*)&sm.hb[1][0][(c * 4 + quad) * 128 + col * 8];
            hfl[c] = *(const short8*)&sm.hb[1][1][(c * 4 + quad) * 128 + col * 8];
        }
        int s  = TT - 1;
        int ta = dir ? 0 : s;
        int i  = col & 3;
        int rr = 4 * (ta / 3) + ta % 3 + (i >> 1);
        int kk = i & 1;
        size_t boff = (size_t)((rr * 2 + kk) * TT + ta) * 128 + dir * 64 + quad * 8;
        float4_t acch = (float4_t){0.f, 0.f, 0.f, 0.f};
        #pragma unroll
        for (int c = 0; c < 2; ++c) {
            short8 ah = *(const short8*)(Bhi + boff + c * 32);
            short8 al = *(const short8*)(Blo + boff + c * 32);
            acch = __builtin_amdgcn_mfma_f32_16x16x32_bf16(ah, hfh[c], acch, 0, 0, 0);
            acch = __builtin_amdgcn_mfma_f32_16x16x32_bf16(ah, hfl[c], acch, 0, 0, 0);
            acch = __builtin_amdgcn_mfma_f32_16x16x32_bf16(al, hfh[c], acch, 0, 0, 0);
        }
        if (quad == 0) {
            #pragma unroll
            for (int reg = 0; reg < 4; ++reg) {
                int r2 = 4 * (ta / 3) + ta % 3 + (reg >> 1);
                sm.out_acc[col][r2 * 2 + (reg & 1)] += acch[reg];
            }
        }
    }
    __syncthreads();

    // ---- epilogue: atomic combine of the two dir-blocks (each adds Cvec/2) ----
    #pragma unroll
    for (int rep = 0; rep < 3; ++rep) {
        int o = rep * 256 + tid;          // 768 = 16 b * 48 cells
        int b = o / 48, c = o % 48;
        atomicAdd(&out[(size_t)bb * 48 + o], sm.out_acc[b][c] + 0.5f * Cvec[c]);
    }
}

extern "C" void kernel_launch(void* const* d_in, const int* in_sizes, int n_in,
                              void* d_out, int out_size, void* d_ws, size_t ws_size,
                              hipStream_t stream) {
    const float* x      = (const float*)d_in[0];
    const float* w_ih_f = (const float*)d_in[1];
    const float* w_hh_f = (const float*)d_in[2];
    const float* b_ih_f = (const float*)d_in[3];
    const float* b_hh_f = (const float*)d_in[4];
    const float* w_ih_b = (const float*)d_in[5];
    const float* w_hh_b = (const float*)d_in[6];
    const float* b_ih_b = (const float*)d_in[7];
    const float* b_hh_b = (const float*)d_in[8];
    const float* fc1_w  = (const float*)d_in[9];
    const float* fc1_b  = (const float*)d_in[10];
    const float* fc2_w  = (const float*)d_in[11];
    const float* fc2_b  = (const float*)d_in[12];
    float* out  = (float*)d_out;

    float*          Cvec = (float*)d_ws;                          // 48 floats (+pad)
    unsigned short* Bhi  = (unsigned short*)((char*)d_ws + 256);  // 110592 ushorts
    unsigned short* Blo  = Bhi + 110592;                          // 110592 ushorts

    hipMemsetAsync(d_out, 0, (size_t)out_size * sizeof(float), stream);
    head_precompute<<<432, 256, 0, stream>>>(fc1_w, fc1_b, fc2_w, fc2_b, Bhi, Blo, Cvec);
    gru_mfma<<<4096, 256, 0, stream>>>(x, w_ih_f, w_hh_f, b_ih_f, b_hh_f,
                                       w_ih_b, w_hh_b, b_ih_b, b_hh_b,
                                       Bhi, Blo, Cvec, out);
}

// Round 5
// 194.536 us; speedup vs baseline: 9.5572x; 1.1098x over previous
//
#include <hip/hip_runtime.h>

#define TT 18

typedef __attribute__((ext_vector_type(8))) short short8;     // 8 bf16 = 4 VGPRs
typedef __attribute__((ext_vector_type(4))) float float4_t;
typedef __attribute__((ext_vector_type(2))) unsigned int uint2_t;

static __device__ __forceinline__ float frcp(float x){ return __builtin_amdgcn_rcpf(x); }
static __device__ __forceinline__ float sigm(float x){ return frcp(1.f + __expf(-x)); }
static __device__ __forceinline__ float tanh_fast(float x){ return fmaf(2.f, frcp(1.f + __expf(-2.f*x)), -1.f); }
// round-to-nearest-even bf16 of f, in the high 16 bits of the result
static __device__ __forceinline__ unsigned rne_bits(float f){
    unsigned u = __float_as_uint(f);
    return u + 0x7fffu + ((u >> 16) & 1u);
}
// fp32 -> bf16 hi (RNE) + bf16 lo (RNE of residual); both returned in LOW 16 bits
static __device__ __forceinline__ void bsplit(float f, unsigned &hi, unsigned &lo){
    unsigned rb = rne_bits(f);
    hi = rb >> 16;
    float fh = __uint_as_float(rb & 0xffff0000u);
    lo = rne_bits(f - fh) >> 16;
}
static __device__ __forceinline__ unsigned pack_hi16(unsigned hi_src, unsigned lo_src){
#if defined(__has_builtin)
#if __has_builtin(__builtin_amdgcn_perm)
    return __builtin_amdgcn_perm(hi_src, lo_src, 0x07060302u);  // [lo.b2,lo.b3,hi.b2,hi.b3]
#else
    return (lo_src >> 16) | (hi_src & 0xffff0000u);
#endif
#else
    return (lo_src >> 16) | (hi_src & 0xffff0000u);
#endif
}

union U8 { short8 s; unsigned u[4]; };

// ---------------------------------------------------------------------------
// Head precompute (verified rounds 1-4): Bhi/Blo bf16 split of
// Bmat[(2r+k)*18+ta][128], Cvec[48].  out[b,r,k] = sum hcat*Bmat + Cvec.
// ---------------------------------------------------------------------------
__global__ __launch_bounds__(256) void head_precompute(
    const float* __restrict__ fc1_w, const float* __restrict__ fc1_b,
    const float* __restrict__ fc2_w, const float* __restrict__ fc2_b,
    unsigned short* __restrict__ Bhi, unsigned short* __restrict__ Blo,
    float* __restrict__ Cvec)
{
    int idx = blockIdx.x * 256 + threadIdx.x;
    if (idx < 24 * 2 * 18 * 128) {
        int jg = idx & 127;
        int t  = (idx >> 7) % 18;
        int k  = (idx / 2304) & 1;
        int r  = idx / 4608;
        float acc = 0.f;
        for (int c = 0; c < 24; ++c) {
            int s = t * 24 + c - r * 18;
            if (s >= 0 && s < 18) acc += fc2_w[k * 18 + s] * fc1_w[c * 128 + jg];
        }
        unsigned hi, lo;
        bsplit(acc, hi, lo);
        Bhi[idx] = (unsigned short)hi;
        Blo[idx] = (unsigned short)lo;
    }
    if (idx < 48) {
        int k = idx & 1, r = idx >> 1;
        float acc = fc2_b[k];
        for (int s = 0; s < 18; ++s)
            acc += fc2_w[k * 18 + s] * fc1_b[(r * 18 + s) % 24];
        Cvec[idx] = acc;
    }
}

// ---------------------------------------------------------------------------
// MFMA GRU, dir-split blocks, augmented-K: gate pre-activations computed
// entirely by MFMA:  [h(64) | x0,x1,1 slots(8)] @ [Whh | Wih,bias]^T.
// Block = 4 waves (jq = gate column group), 16 batches, one dir.
// h: RNE bf16 hi (gates) + lo (head only), double-buffered LDS, 1 barrier/step.
// Elementwise per element: r=sigm(aR); z=sigm(aZ); n=tanh(fma(r,aNH,aNX));
// h'=fma(z,hp-n,n)  -> ~40% fewer VALU insts than round 4.
// ---------------------------------------------------------------------------
struct SMv {
    alignas(16) unsigned short hb[2][2][1024];  // [parity][hi/lo][(j>>3)*128+b*8+(j&7)]
    uint2_t x2[16][18];                         // per (b,t): {x0h|x0l<<16, x1h|x1l<<16}
    float out_acc[16][49];                      // stride 49: conflict-free RMW
};

__global__ __launch_bounds__(256, 4) void gru_mfma(
    const float* __restrict__ x,
    const float* __restrict__ w_ih_f, const float* __restrict__ w_hh_f,
    const float* __restrict__ b_ih_f, const float* __restrict__ b_hh_f,
    const float* __restrict__ w_ih_b, const float* __restrict__ w_hh_b,
    const float* __restrict__ b_ih_b, const float* __restrict__ b_hh_b,
    const unsigned short* __restrict__ Bhi, const unsigned short* __restrict__ Blo,
    const float* __restrict__ Cvec, float* __restrict__ out)
{
    __shared__ SMv sm;
    const int tid  = threadIdx.x;
    const int lane = tid & 63;
    const int jq   = tid >> 6;      // wave = gate column group (16 j's)
    const int col  = lane & 15;     // batch (B/C col); gate row at A-load
    const int quad = lane >> 4;
    const int bi   = blockIdx.x;
    const int dir  = bi >> 11;
    const int bb   = (bi & 2047) * 16;
    const bool q0  = (quad == 0);

    const float* __restrict__ wih = dir ? w_ih_b : w_ih_f;
    const float* __restrict__ whh = dir ? w_hh_b : w_hh_f;
    const float* __restrict__ bih = dir ? b_ih_b : b_ih_f;
    const float* __restrict__ bhh = dir ? b_hh_b : b_hh_f;

    // ---- stage x (pre-split bf16 hi/lo), zero parity-1 h buffers, out_acc ----
    #pragma unroll
    for (int p = tid; p < 288; p += 256) {
        int b = p / 18, t = p % 18;
        const float* xp = x + (size_t)(bb + b) * 36 + t * 2;
        unsigned h0, l0, h1, l1;
        bsplit(xp[0], h0, l0);
        bsplit(xp[1], h1, l1);
        uint2_t s2; s2[0] = h0 | (l0 << 16); s2[1] = h1 | (l1 << 16);
        sm.x2[b][t] = s2;
    }
    {
        unsigned* z = (unsigned*)&sm.hb[1][0][0];
        #pragma unroll
        for (int o = 0; o < 4; ++o) z[tid + o * 256] = 0u;
    }
    for (int o = tid; o < 16 * 49; o += 256) ((float*)sm.out_acc)[o] = 0.f;

    // ---- persistent W A-fragments (RNE bf16), h-part chunks 0..1 ----
    // A[m=col][k=quad*8+e+c*32] = whh[(ty*64 + jq*16 + col)*64 + k]
    short8 wf[3][2];
    #pragma unroll
    for (int ty = 0; ty < 3; ++ty) {
        int g = ty * 64 + jq * 16 + col;
        #pragma unroll
        for (int c = 0; c < 2; ++c) {
            const float* p = whh + g * 64 + c * 32 + quad * 8;
            float4_t f0 = *(const float4_t*)p;
            float4_t f1 = *(const float4_t*)(p + 4);
            short8 s;
            #pragma unroll
            for (int e = 0; e < 8; ++e) {
                float f = (e < 4) ? f0[e] : f1[e - 4];
                s[e] = (short)(rne_bits(f) >> 16);
            }
            wf[ty][c] = s;
        }
    }

    // ---- augmented-K chunk-2 A-frags: c2[0]=r, c2[1]=z, c2[2]=nh, c2[3]=nx ----
    // slots e0..7 (only quad==0 lanes nonzero):
    //   rz/nx: [w0h,w0h,w0l,w1h,w1h,w1l,b_hi,b_lo];  nh: [0..0, bhh_hi, bhh_lo]
    short8 c2[4];
    {
        #pragma unroll
        for (int ty = 0; ty < 2; ++ty) {      // r, z
            int g = ty * 64 + jq * 16 + col;
            unsigned w0h, w0l, w1h, w1l, bh, bl;
            bsplit(wih[2 * g],     w0h, w0l);
            bsplit(wih[2 * g + 1], w1h, w1l);
            bsplit(bih[g] + bhh[g], bh, bl);
            U8 f;
            f.u[0] = q0 ? (w0h | (w0h << 16)) : 0u;
            f.u[1] = q0 ? (w0l | (w1h << 16)) : 0u;
            f.u[2] = q0 ? (w1h | (w1l << 16)) : 0u;
            f.u[3] = q0 ? (bh  | (bl  << 16)) : 0u;
            c2[ty] = f.s;
        }
        int g = 128 + jq * 16 + col;          // n
        unsigned w0h, w0l, w1h, w1l, bxh, bxl, bhh_h, bhh_l;
        bsplit(wih[2 * g],     w0h, w0l);
        bsplit(wih[2 * g + 1], w1h, w1l);
        bsplit(bih[g], bxh, bxl);
        bsplit(bhh[g], bhh_h, bhh_l);
        U8 fn;                                 // nh: h-side bias only
        fn.u[0] = 0u; fn.u[1] = 0u; fn.u[2] = 0u;
        fn.u[3] = q0 ? (bhh_h | (bhh_l << 16)) : 0u;
        c2[2] = fn.s;
        U8 fx;                                 // nx: x-weights + input bias
        fx.u[0] = q0 ? (w0h | (w0h << 16)) : 0u;
        fx.u[1] = q0 ? (w0l | (w1h << 16)) : 0u;
        fx.u[2] = q0 ? (w1h | (w1l << 16)) : 0u;
        fx.u[3] = q0 ? (bxh | (bxl << 16)) : 0u;
        c2[3] = fx.s;
    }

    float hprev[4] = {0.f, 0.f, 0.f, 0.f};

    __syncthreads();

    auto step = [&](int t, int pr, int pw) {
        const bool myhead = (t > 0) && (((t - 1) & 3) == jq);

        // (0) head A-frag loads issued early (consumed at step bottom)
        int ta_h = 0, base_h = 0;
        size_t boff = 0;
        short8 hA0, hA1, lA0, lA1, hfl0, hfl1;
        if (myhead) {
            int s  = t - 1;
            ta_h   = dir ? (TT - 1 - s) : s;
            base_h = 4 * (ta_h / 3) + ta_h % 3;
            int i  = col & 3;
            int rr = base_h + (i >> 1);
            int kk = i & 1;
            boff = (size_t)((rr * 2 + kk) * TT + ta_h) * 128 + dir * 64 + quad * 8;
            hA0 = *(const short8*)(Bhi + boff);
            hA1 = *(const short8*)(Bhi + boff + 32);
            hfl0 = *(const short8*)&sm.hb[pr][1][(0 * 4 + quad) * 128 + col * 8];
            hfl1 = *(const short8*)&sm.hb[pr][1][(1 * 4 + quad) * 128 + col * 8];
        }

        // (1) h hi fragments of step t-1
        short8 hfh[2];
        #pragma unroll
        for (int c = 0; c < 2; ++c)
            hfh[c] = *(const short8*)&sm.hb[pr][0][(c * 4 + quad) * 128 + col * 8];

        // (2) chunk-2 B-frag: [x0h,x0l,x0h,x1h,x1l,x1h,1,1] on quad 0
        const int tx = dir ? (TT - 1 - t) : t;
        short8 b2f;
        {
            uint2_t xs = sm.x2[col][tx];
            U8 B;
            B.u[0] = q0 ? xs[0] : 0u;
            B.u[1] = q0 ? ((xs[0] & 0xffffu) | (xs[1] << 16)) : 0u;
            B.u[2] = q0 ? ((xs[1] >> 16) | (xs[1] << 16)) : 0u;
            B.u[3] = q0 ? 0x3F803F80u : 0u;
            b2f = B.s;
        }

        // (3) gate GEMM: 3 types x 2 h-chunks + 4 chunk-2 = 10 MFMAs
        float4_t aR  = (float4_t){0.f,0.f,0.f,0.f};
        float4_t aZ  = (float4_t){0.f,0.f,0.f,0.f};
        float4_t aNH = (float4_t){0.f,0.f,0.f,0.f};
        float4_t aNX = (float4_t){0.f,0.f,0.f,0.f};
        #pragma unroll
        for (int c = 0; c < 2; ++c) {
            aR  = __builtin_amdgcn_mfma_f32_16x16x32_bf16(wf[0][c], hfh[c], aR,  0, 0, 0);
            aZ  = __builtin_amdgcn_mfma_f32_16x16x32_bf16(wf[1][c], hfh[c], aZ,  0, 0, 0);
            aNH = __builtin_amdgcn_mfma_f32_16x16x32_bf16(wf[2][c], hfh[c], aNH, 0, 0, 0);
        }
        aR  = __builtin_amdgcn_mfma_f32_16x16x32_bf16(c2[0], b2f, aR,  0, 0, 0);
        aZ  = __builtin_amdgcn_mfma_f32_16x16x32_bf16(c2[1], b2f, aZ,  0, 0, 0);
        aNH = __builtin_amdgcn_mfma_f32_16x16x32_bf16(c2[2], b2f, aNH, 0, 0, 0);
        aNX = __builtin_amdgcn_mfma_f32_16x16x32_bf16(c2[3], b2f, aNX, 0, 0, 0);

        // (4) elementwise; RNE hi + residual lo; b64 writes to parity pw
        unsigned rh[4], rl[4];
        #pragma unroll
        for (int reg = 0; reg < 4; ++reg) {
            float r = sigm(aR[reg]);
            float z = sigm(aZ[reg]);
            float n = tanh_fast(fmaf(r, aNH[reg], aNX[reg]));
            float hnew = fmaf(z, hprev[reg] - n, n);
            hprev[reg] = hnew;
            unsigned rb = rne_bits(hnew);
            rh[reg] = rb;
            float fh = __uint_as_float(rb & 0xffff0000u);
            rl[reg] = rne_bits(hnew - fh);
        }
        int woff = (jq * 2 + (quad >> 1)) * 128 + col * 8 + (quad & 1) * 4;
        uint2_t dh, dl;
        dh[0] = pack_hi16(rh[1], rh[0]);
        dh[1] = pack_hi16(rh[3], rh[2]);
        dl[0] = pack_hi16(rl[1], rl[0]);
        dl[1] = pack_hi16(rl[3], rl[2]);
        *(uint2_t*)&sm.hb[pw][0][woff] = dh;
        *(uint2_t*)&sm.hb[pw][1][woff] = dl;

        // (5) fused head for s = t-1 (A loads from (0) have drained by now)
        if (myhead) {
            lA0 = *(const short8*)(Blo + boff);
            lA1 = *(const short8*)(Blo + boff + 32);
            float4_t acch = (float4_t){0.f,0.f,0.f,0.f};
            acch = __builtin_amdgcn_mfma_f32_16x16x32_bf16(hA0, hfh[0], acch, 0, 0, 0);
            acch = __builtin_amdgcn_mfma_f32_16x16x32_bf16(hA1, hfh[1], acch, 0, 0, 0);
            acch = __builtin_amdgcn_mfma_f32_16x16x32_bf16(hA0, hfl0,   acch, 0, 0, 0);
            acch = __builtin_amdgcn_mfma_f32_16x16x32_bf16(hA1, hfl1,   acch, 0, 0, 0);
            acch = __builtin_amdgcn_mfma_f32_16x16x32_bf16(lA0, hfh[0], acch, 0, 0, 0);
            acch = __builtin_amdgcn_mfma_f32_16x16x32_bf16(lA1, hfh[1], acch, 0, 0, 0);
            if (q0) {
                #pragma unroll
                for (int reg = 0; reg < 4; ++reg) {
                    int r2 = base_h + (reg >> 1);
                    sm.out_acc[col][r2 * 2 + (reg & 1)] += acch[reg];
                }
            }
        }
        __syncthreads();
    };

    #pragma unroll 1
    for (int tt = 0; tt < 9; ++tt) {
        step(2 * tt,     1, 0);
        step(2 * tt + 1, 0, 1);
    }

    // ---- final head for s = 17 (h17 in parity 1), wave jq == 1 ----
    if (jq == ((TT - 1) & 3)) {
        int s  = TT - 1;
        int ta = dir ? 0 : s;
        int base_h = 4 * (ta / 3) + ta % 3;
        int i  = col & 3;
        int rr = base_h + (i >> 1);
        int kk = i & 1;
        size_t boff = (size_t)((rr * 2 + kk) * TT + ta) * 128 + dir * 64 + quad * 8;
        short8 hA0 = *(const short8*)(Bhi + boff);
        short8 hA1 = *(const short8*)(Bhi + boff + 32);
        short8 lA0 = *(const short8*)(Blo + boff);
        short8 lA1 = *(const short8*)(Blo + boff + 32);
        short8 hfh0 = *(const short8*)&sm.hb[1][0][(0 * 4 + quad) * 128 + col * 8];
        short8 hfh1 = *(const short8*)&sm.hb[1][0][(1 * 4 + quad) * 128 + col * 8];
        short8 hfl0 = *(const short8*)&sm.hb[1][1][(0 * 4 + quad) * 128 + col * 8];
        short8 hfl1 = *(const short8*)&sm.hb[1][1][(1 * 4 + quad) * 128 + col * 8];
        float4_t acch = (float4_t){0.f,0.f,0.f,0.f};
        acch = __builtin_amdgcn_mfma_f32_16x16x32_bf16(hA0, hfh0, acch, 0, 0, 0);
        acch = __builtin_amdgcn_mfma_f32_16x16x32_bf16(hA1, hfh1, acch, 0, 0, 0);
        acch = __builtin_amdgcn_mfma_f32_16x16x32_bf16(hA0, hfl0, acch, 0, 0, 0);
        acch = __builtin_amdgcn_mfma_f32_16x16x32_bf16(hA1, hfl1, acch, 0, 0, 0);
        acch = __builtin_amdgcn_mfma_f32_16x16x32_bf16(lA0, hfh0, acch, 0, 0, 0);
        acch = __builtin_amdgcn_mfma_f32_16x16x32_bf16(lA1, hfh1, acch, 0, 0, 0);
        if (q0) {
            #pragma unroll
            for (int reg = 0; reg < 4; ++reg) {
                int r2 = base_h + (reg >> 1);
                sm.out_acc[col][r2 * 2 + (reg & 1)] += acch[reg];
            }
        }
    }
    __syncthreads();

    // ---- epilogue: atomic combine of the two dir-blocks (each adds Cvec/2) ----
    #pragma unroll
    for (int rep = 0; rep < 3; ++rep) {
        int o = rep * 256 + tid;          // 768 = 16 b * 48 cells
        int b = o / 48, c = o % 48;
        atomicAdd(&out[(size_t)bb * 48 + o], sm.out_acc[b][c] + 0.5f * Cvec[c]);
    }
}

extern "C" void kernel_launch(void* const* d_in, const int* in_sizes, int n_in,
                              void* d_out, int out_size, void* d_ws, size_t ws_size,
                              hipStream_t stream) {
    const float* x      = (const float*)d_in[0];
    const float* w_ih_f = (const float*)d_in[1];
    const float* w_hh_f = (const float*)d_in[2];
    const float* b_ih_f = (const float*)d_in[3];
    const float* b_hh_f = (const float*)d_in[4];
    const float* w_ih_b = (const float*)d_in[5];
    const float* w_hh_b = (const float*)d_in[6];
    const float* b_ih_b = (const float*)d_in[7];
    const float* b_hh_b = (const float*)d_in[8];
    const float* fc1_w  = (const float*)d_in[9];
    const float* fc1_b  = (const float*)d_in[10];
    const float* fc2_w  = (const float*)d_in[11];
    const float* fc2_b  = (const float*)d_in[12];
    float* out  = (float*)d_out;

    float*          Cvec = (float*)d_ws;                          // 48 floats (+pad)
    unsigned short* Bhi  = (unsigned short*)((char*)d_ws + 256);  // 110592 ushorts
    unsigned short* Blo  = Bhi + 110592;                          // 110592 ushorts

    hipMemsetAsync(d_out, 0, (size_t)out_size * sizeof(float), stream);
    head_precompute<<<432, 256, 0, stream>>>(fc1_w, fc1_b, fc2_w, fc2_b, Bhi, Blo, Cvec);
    gru_mfma<<<4096, 256, 0, stream>>>(x, w_ih_f, w_hh_f, b_ih_f, b_hh_f,
                                       w_ih_b, w_hh_b, b_ih_b, b_hh_b,
                                       Bhi, Blo, Cvec, out);
}

// Round 6
// 193.566 us; speedup vs baseline: 9.6051x; 1.0050x over previous
//
#include <hip/hip_runtime.h>

#define TT 18

typedef __attribute__((ext_vector_type(8))) short short8;     // 8 bf16 = 4 VGPRs
typedef __attribute__((ext_vector_type(4))) float float4_t;
typedef __attribute__((ext_vector_type(2))) unsigned int uint2_t;

#if defined(__has_builtin)
#if __has_builtin(__builtin_amdgcn_exp2f)
#define FEXP2(x) __builtin_amdgcn_exp2f(x)
#else
#define FEXP2(x) exp2f(x)
#endif
#else
#define FEXP2(x) exp2f(x)
#endif

static __device__ __forceinline__ float frcp(float x){ return __builtin_amdgcn_rcpf(x); }
// round-to-nearest-even bf16 of f, in the high 16 bits of the result
static __device__ __forceinline__ unsigned rne_bits(float f){
    unsigned u = __float_as_uint(f);
    return u + 0x7fffu + ((u >> 16) & 1u);
}
// fp32 -> bf16 hi (RNE) + bf16 lo (RNE of residual); both in LOW 16 bits
static __device__ __forceinline__ void bsplit(float f, unsigned &hi, unsigned &lo){
    unsigned rb = rne_bits(f);
    hi = rb >> 16;
    float fh = __uint_as_float(rb & 0xffff0000u);
    lo = rne_bits(f - fh) >> 16;
}
static __device__ __forceinline__ unsigned pack_hi16(unsigned hi_src, unsigned lo_src){
#if defined(__has_builtin)
#if __has_builtin(__builtin_amdgcn_perm)
    return __builtin_amdgcn_perm(hi_src, lo_src, 0x07060302u);
#else
    return (lo_src >> 16) | (hi_src & 0xffff0000u);
#endif
#else
    return (lo_src >> 16) | (hi_src & 0xffff0000u);
#endif
}

union U8 { short8 s; unsigned u[4]; };

#define MFMA16(A,B,C) __builtin_amdgcn_mfma_f32_16x16x32_bf16((A),(B),(C),0,0,0)

// ---------------------------------------------------------------------------
// Head precompute (verified rounds 1-5): Bhi/Blo bf16 split of
// Bmat[(2r+k)*18+ta][128], Cvec[48].  out[b,r,k] = sum hcat*Bmat + Cvec.
// ---------------------------------------------------------------------------
__global__ __launch_bounds__(256) void head_precompute(
    const float* __restrict__ fc1_w, const float* __restrict__ fc1_b,
    const float* __restrict__ fc2_w, const float* __restrict__ fc2_b,
    unsigned short* __restrict__ Bhi, unsigned short* __restrict__ Blo,
    float* __restrict__ Cvec)
{
    int idx = blockIdx.x * 256 + threadIdx.x;
    if (idx < 24 * 2 * 18 * 128) {
        int jg = idx & 127;
        int t  = (idx >> 7) % 18;
        int k  = (idx / 2304) & 1;
        int r  = idx / 4608;
        float acc = 0.f;
        for (int c = 0; c < 24; ++c) {
            int s = t * 24 + c - r * 18;
            if (s >= 0 && s < 18) acc += fc2_w[k * 18 + s] * fc1_w[c * 128 + jg];
        }
        unsigned hi, lo;
        bsplit(acc, hi, lo);
        Bhi[idx] = (unsigned short)hi;
        Blo[idx] = (unsigned short)lo;
    }
    if (idx < 48) {
        int k = idx & 1, r = idx >> 1;
        float acc = fc2_b[k];
        for (int s = 0; s < 18; ++s)
            acc += fc2_w[k * 18 + s] * fc1_b[(r * 18 + s) % 24];
        Cvec[idx] = acc;
    }
}

// ---------------------------------------------------------------------------
// MFMA GRU, dir-split blocks, augmented-K, log2e-folded weights.
// Block = 4 waves (jq = gate column group), 16 batches, one dir.
// chunk-2 A-frags (c2a) and B-frags (b2x) live in LDS; zero page for quads 1-3.
// h: RNE bf16 hi (gates) + truncated lo (head), double-buffered, 1 barrier/step.
// ---------------------------------------------------------------------------
struct SMv {
    alignas(16) unsigned short hb[2][2][1024];   // 8 KiB [parity][hi/lo][(j>>3)*128+b*8+(j&7)]
    alignas(16) unsigned short b2x[2][64][8];    // 2 KiB [parity][lane][slot]
    alignas(16) unsigned short c2a[4][4][16][8]; // 4 KiB [jq][type][col][slot]
    alignas(16) unsigned short zero16[8];        // 16 B zero page
    uint2_t x2[16][18];                          // per (b,t): {x0h|x0l<<16, x1h|x1l<<16}
    float out_acc[16][49];                       // stride 49: conflict-free RMW
};

__global__ __launch_bounds__(256, 4) void gru_mfma(
    const float* __restrict__ x,
    const float* __restrict__ w_ih_f, const float* __restrict__ w_hh_f,
    const float* __restrict__ b_ih_f, const float* __restrict__ b_hh_f,
    const float* __restrict__ w_ih_b, const float* __restrict__ w_hh_b,
    const float* __restrict__ b_ih_b, const float* __restrict__ b_hh_b,
    const unsigned short* __restrict__ Bhi, const unsigned short* __restrict__ Blo,
    const float* __restrict__ Cvec, float* __restrict__ out)
{
    __shared__ SMv sm;
    const int tid  = threadIdx.x;
    const int lane = tid & 63;
    const int jq   = tid >> 6;
    const int col  = lane & 15;
    const int quad = lane >> 4;
    const int bi   = blockIdx.x;
    const int dir  = bi >> 11;
    const int bb   = (bi & 2047) * 16;
    const bool q0  = (quad == 0);

    const float* __restrict__ wih = dir ? w_ih_b : w_ih_f;
    const float* __restrict__ whh = dir ? w_hh_b : w_hh_f;
    const float* __restrict__ bih = dir ? b_ih_b : b_ih_f;
    const float* __restrict__ bhh = dir ? b_hh_b : b_hh_f;

    const float L1 = 1.4426950408889634f;   // log2(e)
    const float L2 = 2.8853900817779268f;   // 2*log2(e)

    // ---- zero LDS regions ----
    {
        unsigned* z = (unsigned*)&sm.hb[1][0][0];
        #pragma unroll
        for (int o = 0; o < 4; ++o) z[tid + o * 256] = 0u;
        unsigned* z2 = (unsigned*)&sm.b2x[0][0][0];
        #pragma unroll
        for (int o = 0; o < 2; ++o) z2[tid + o * 256] = 0u;
        if (tid < 4) ((unsigned*)sm.zero16)[tid] = 0u;
    }
    for (int o = tid; o < 16 * 49; o += 256) ((float*)sm.out_acc)[o] = 0.f;

    // ---- stage x (pre-split bf16 hi/lo) ----
    for (int p = tid; p < 288; p += 256) {
        int b = p / 18, t = p % 18;
        const float* xp = x + (size_t)(bb + b) * 36 + t * 2;
        unsigned h0, l0, h1, l1;
        bsplit(xp[0], h0, l0);
        bsplit(xp[1], h1, l1);
        uint2_t s2; s2[0] = h0 | (l0 << 16); s2[1] = h1 | (l1 << 16);
        sm.x2[b][t] = s2;
    }

    // ---- b2x parity-1 init for t=0 ----
    if (tid < 16) {
        int tx0 = dir ? (TT - 1) : 0;
        const float* xp = x + (size_t)(bb + tid) * 36 + tx0 * 2;
        unsigned h0, l0, h1, l1;
        bsplit(xp[0], h0, l0);
        bsplit(xp[1], h1, l1);
        U8 B;
        B.u[0] = h0 | (l0 << 16);
        B.u[1] = h0 | (h1 << 16);
        B.u[2] = l1 | (h1 << 16);
        B.u[3] = 0x3F803F80u;
        *(short8*)&sm.b2x[1][tid][0] = B.s;
    }

    // ---- c2a build (quad-0 threads): types 0=r(L1) 1=z(L1) 2=nh-bias(L2) 3=nx(L2) ----
    if (q0) {
        int g0 = jq * 16 + col;
        #pragma unroll
        for (int ty = 0; ty < 2; ++ty) {
            int g = ty * 64 + g0;
            unsigned w0h, w0l, w1h, w1l, bh, bl;
            bsplit(L1 * wih[2 * g],     w0h, w0l);
            bsplit(L1 * wih[2 * g + 1], w1h, w1l);
            bsplit(L1 * (bih[g] + bhh[g]), bh, bl);
            U8 f;
            f.u[0] = w0h | (w0h << 16);
            f.u[1] = w0l | (w1h << 16);
            f.u[2] = w1h | (w1l << 16);
            f.u[3] = bh  | (bl  << 16);
            *(short8*)&sm.c2a[jq][ty][col][0] = f.s;
        }
        {   // nh: h-side bias only
            unsigned bh, bl;
            bsplit(L2 * bhh[128 + g0], bh, bl);
            U8 f;
            f.u[0] = 0u; f.u[1] = 0u; f.u[2] = 0u;
            f.u[3] = bh | (bl << 16);
            *(short8*)&sm.c2a[jq][2][col][0] = f.s;
        }
        {   // nx
            int g = 128 + g0;
            unsigned w0h, w0l, w1h, w1l, bh, bl;
            bsplit(L2 * wih[2 * g],     w0h, w0l);
            bsplit(L2 * wih[2 * g + 1], w1h, w1l);
            bsplit(L2 * bih[g], bh, bl);
            U8 f;
            f.u[0] = w0h | (w0h << 16);
            f.u[1] = w0l | (w1h << 16);
            f.u[2] = w1h | (w1l << 16);
            f.u[3] = bh  | (bl  << 16);
            *(short8*)&sm.c2a[jq][3][col][0] = f.s;
        }
    }

    // ---- persistent W A-frags (RNE bf16, log2e-scaled): r,z by L1; nh by L2 ----
    short8 wf[3][2];
    #pragma unroll
    for (int ty = 0; ty < 3; ++ty) {
        float sc = (ty == 2) ? L2 : L1;
        int g = ty * 64 + jq * 16 + col;
        #pragma unroll
        for (int c = 0; c < 2; ++c) {
            const float* p = whh + g * 64 + c * 32 + quad * 8;
            float4_t f0 = *(const float4_t*)p;
            float4_t f1 = *(const float4_t*)(p + 4);
            short8 s;
            #pragma unroll
            for (int e = 0; e < 8; ++e) {
                float f = (e < 4) ? f0[e] : f1[e - 4];
                s[e] = (short)(rne_bits(sc * f) >> 16);
            }
            wf[ty][c] = s;
        }
    }

    // loop-invariant c2a read pointers (zero page for quads 1-3)
    const unsigned short* c2p0 = q0 ? &sm.c2a[jq][0][col][0] : sm.zero16;
    const unsigned short* c2p1 = q0 ? &sm.c2a[jq][1][col][0] : sm.zero16;
    const unsigned short* c2p2 = q0 ? &sm.c2a[jq][2][col][0] : sm.zero16;
    const unsigned short* c2p3 = q0 ? &sm.c2a[jq][3][col][0] : sm.zero16;

    float hprev[4] = {0.f, 0.f, 0.f, 0.f};

    __syncthreads();

    auto step = [&](int t, int pr, int pw) {
        // (1) reads: h hi frags, chunk-2 B frag, chunk-2 A frags
        short8 hfh[2];
        hfh[0] = *(const short8*)&sm.hb[pr][0][quad * 128 + col * 8];
        hfh[1] = *(const short8*)&sm.hb[pr][0][(4 + quad) * 128 + col * 8];
        short8 b2f  = *(const short8*)&sm.b2x[pr][lane][0];
        short8 c2f0 = *(const short8*)c2p0;
        short8 c2f1 = *(const short8*)c2p1;
        short8 c2f2 = *(const short8*)c2p2;
        short8 c2f3 = *(const short8*)c2p3;

        // (2) gate GEMM: 6 h-MFMAs + 4 chunk-2 MFMAs
        float4_t aR  = (float4_t){0.f,0.f,0.f,0.f};
        float4_t aZ  = (float4_t){0.f,0.f,0.f,0.f};
        float4_t aNH = (float4_t){0.f,0.f,0.f,0.f};
        float4_t aNX = (float4_t){0.f,0.f,0.f,0.f};
        aR  = MFMA16(wf[0][0], hfh[0], aR);
        aR  = MFMA16(wf[0][1], hfh[1], aR);
        aR  = MFMA16(c2f0,     b2f,    aR);
        aZ  = MFMA16(wf[1][0], hfh[0], aZ);
        aZ  = MFMA16(wf[1][1], hfh[1], aZ);
        aZ  = MFMA16(c2f1,     b2f,    aZ);
        aNH = MFMA16(wf[2][0], hfh[0], aNH);
        aNH = MFMA16(wf[2][1], hfh[1], aNH);
        aNH = MFMA16(c2f2,     b2f,    aNH);
        aNX = MFMA16(c2f3,     b2f,    aNX);

        // (3) elementwise (log2e-folded): exp2 with free neg modifier
        unsigned rh[4], rl[4];
        #pragma unroll
        for (int reg = 0; reg < 4; ++reg) {
            float r = frcp(1.f + FEXP2(-aR[reg]));
            float z = frcp(1.f + FEXP2(-aZ[reg]));
            float a = fmaf(r, aNH[reg], aNX[reg]);
            float n = fmaf(2.f, frcp(1.f + FEXP2(-a)), -1.f);
            float hnew = fmaf(z, hprev[reg] - n, n);
            hprev[reg] = hnew;
            unsigned rb = rne_bits(hnew);
            rh[reg] = rb;
            rl[reg] = __float_as_uint(hnew - __uint_as_float(rb & 0xffff0000u));
        }
        int woff = (jq * 2 + (quad >> 1)) * 128 + col * 8 + (quad & 1) * 4;
        uint2_t dh, dl;
        dh[0] = pack_hi16(rh[1], rh[0]);
        dh[1] = pack_hi16(rh[3], rh[2]);
        dl[0] = pack_hi16(rl[1], rl[0]);
        dl[1] = pack_hi16(rl[3], rl[2]);
        *(uint2_t*)&sm.hb[pw][0][woff] = dh;
        *(uint2_t*)&sm.hb[pw][1][woff] = dl;

        // (4) b2x writer for step t+1 (wave 0, quad-0 lanes)
        if (jq == 0 && q0) {
            int tn  = (t + 1 < TT) ? (t + 1) : (TT - 1);
            int txn = dir ? (TT - 1 - tn) : tn;
            uint2_t xs = sm.x2[col][txn];
            U8 B;
            B.u[0] = xs[0];
            B.u[1] = (xs[0] & 0xffffu) | (xs[1] << 16);
            B.u[2] = (xs[1] >> 16) | (xs[1] << 16);
            B.u[3] = 0x3F803F80u;
            *(short8*)&sm.b2x[pw][lane][0] = B.s;
        }

        // (5) fused head for s = t-1, rotating wave
        if (t > 0 && ((t - 1) & 3) == jq) {
            int s  = t - 1;
            int ta = dir ? (TT - 1 - s) : s;
            int base_h = 4 * (ta / 3) + ta % 3;
            int i  = col & 3;
            int rr = base_h + (i >> 1);
            int kk = i & 1;
            size_t boff = (size_t)((rr * 2 + kk) * TT + ta) * 128 + dir * 64 + quad * 8;
            short8 hA0 = *(const short8*)(Bhi + boff);
            short8 hA1 = *(const short8*)(Bhi + boff + 32);
            short8 lA0 = *(const short8*)(Blo + boff);
            short8 lA1 = *(const short8*)(Blo + boff + 32);
            short8 hfl0 = *(const short8*)&sm.hb[pr][1][quad * 128 + col * 8];
            short8 hfl1 = *(const short8*)&sm.hb[pr][1][(4 + quad) * 128 + col * 8];
            float4_t acch = (float4_t){0.f,0.f,0.f,0.f};
            acch = MFMA16(hA0, hfh[0], acch);
            acch = MFMA16(hA1, hfh[1], acch);
            acch = MFMA16(hA0, hfl0,   acch);
            acch = MFMA16(hA1, hfl1,   acch);
            acch = MFMA16(lA0, hfh[0], acch);
            acch = MFMA16(lA1, hfh[1], acch);
            if (q0) {
                #pragma unroll
                for (int reg = 0; reg < 4; ++reg) {
                    int r2 = base_h + (reg >> 1);
                    sm.out_acc[col][r2 * 2 + (reg & 1)] += acch[reg];
                }
            }
        }
        __syncthreads();
    };

    #pragma unroll 1
    for (int tt = 0; tt < 9; ++tt) {
        step(2 * tt,     1, 0);
        step(2 * tt + 1, 0, 1);
    }

    // ---- final head for s = 17 (h17 in parity 1), wave jq == 1 ----
    if (jq == ((TT - 1) & 3)) {
        int s  = TT - 1;
        int ta = dir ? 0 : s;
        int base_h = 4 * (ta / 3) + ta % 3;
        int i  = col & 3;
        int rr = base_h + (i >> 1);
        int kk = i & 1;
        size_t boff = (size_t)((rr * 2 + kk) * TT + ta) * 128 + dir * 64 + quad * 8;
        short8 hA0 = *(const short8*)(Bhi + boff);
        short8 hA1 = *(const short8*)(Bhi + boff + 32);
        short8 lA0 = *(const short8*)(Blo + boff);
        short8 lA1 = *(const short8*)(Blo + boff + 32);
        short8 hfh0 = *(const short8*)&sm.hb[1][0][quad * 128 + col * 8];
        short8 hfh1 = *(const short8*)&sm.hb[1][0][(4 + quad) * 128 + col * 8];
        short8 hfl0 = *(const short8*)&sm.hb[1][1][quad * 128 + col * 8];
        short8 hfl1 = *(const short8*)&sm.hb[1][1][(4 + quad) * 128 + col * 8];
        float4_t acch = (float4_t){0.f,0.f,0.f,0.f};
        acch = MFMA16(hA0, hfh0, acch);
        acch = MFMA16(hA1, hfh1, acch);
        acch = MFMA16(hA0, hfl0, acch);
        acch = MFMA16(hA1, hfl1, acch);
        acch = MFMA16(lA0, hfh0, acch);
        acch = MFMA16(lA1, hfh1, acch);
        if (q0) {
            #pragma unroll
            for (int reg = 0; reg < 4; ++reg) {
                int r2 = base_h + (reg >> 1);
                sm.out_acc[col][r2 * 2 + (reg & 1)] += acch[reg];
            }
        }
    }
    __syncthreads();

    // ---- epilogue: atomic combine of the two dir-blocks (each adds Cvec/2) ----
    #pragma unroll
    for (int rep = 0; rep < 3; ++rep) {
        int o = rep * 256 + tid;          // 768 = 16 b * 48 cells
        int b = o / 48, c = o % 48;
        atomicAdd(&out[(size_t)bb * 48 + o], sm.out_acc[b][c] + 0.5f * Cvec[c]);
    }
}

extern "C" void kernel_launch(void* const* d_in, const int* in_sizes, int n_in,
                              void* d_out, int out_size, void* d_ws, size_t ws_size,
                              hipStream_t stream) {
    const float* x      = (const float*)d_in[0];
    const float* w_ih_f = (const float*)d_in[1];
    const float* w_hh_f = (const float*)d_in[2];
    const float* b_ih_f = (const float*)d_in[3];
    const float* b_hh_f = (const float*)d_in[4];
    const float* w_ih_b = (const float*)d_in[5];
    const float* w_hh_b = (const float*)d_in[6];
    const float* b_ih_b = (const float*)d_in[7];
    const float* b_hh_b = (const float*)d_in[8];
    const float* fc1_w  = (const float*)d_in[9];
    const float* fc1_b  = (const float*)d_in[10];
    const float* fc2_w  = (const float*)d_in[11];
    const float* fc2_b  = (const float*)d_in[12];
    float* out  = (float*)d_out;

    float*          Cvec = (float*)d_ws;                          // 48 floats (+pad)
    unsigned short* Bhi  = (unsigned short*)((char*)d_ws + 256);  // 110592 ushorts
    unsigned short* Blo  = Bhi + 110592;                          // 110592 ushorts

    hipMemsetAsync(d_out, 0, (size_t)out_size * sizeof(float), stream);
    head_precompute<<<432, 256, 0, stream>>>(fc1_w, fc1_b, fc2_w, fc2_b, Bhi, Blo, Cvec);
    gru_mfma<<<4096, 256, 0, stream>>>(x, w_ih_f, w_hh_f, b_ih_f, b_hh_f,
                                       w_ih_b, w_hh_b, b_ih_b, b_hh_b,
                                       Bhi, Blo, Cvec, out);
}

// Round 8
// 181.593 us; speedup vs baseline: 10.2384x; 1.0659x over previous
//
#include <hip/hip_runtime.h>

#define TT 18

typedef __attribute__((ext_vector_type(8))) short short8;     // 8 bf16 = 4 VGPRs
typedef __attribute__((ext_vector_type(4))) float float4_t;
typedef __attribute__((ext_vector_type(2))) float float2_t;
typedef __attribute__((ext_vector_type(2))) unsigned int uint2_t;

#if defined(__has_builtin)
#if __has_builtin(__builtin_amdgcn_exp2f)
#define FEXP2(x) __builtin_amdgcn_exp2f(x)
#else
#define FEXP2(x) exp2f(x)
#endif
#else
#define FEXP2(x) exp2f(x)
#endif

static __device__ __forceinline__ float frcp(float x){ return __builtin_amdgcn_rcpf(x); }
static __device__ __forceinline__ unsigned rne_bits(float f){
    unsigned u = __float_as_uint(f);
    return u + 0x7fffu + ((u >> 16) & 1u);
}
static __device__ __forceinline__ void bsplit(float f, unsigned &hi, unsigned &lo){
    unsigned rb = rne_bits(f);
    hi = rb >> 16;
    float fh = __uint_as_float(rb & 0xffff0000u);
    lo = rne_bits(f - fh) >> 16;
}
static __device__ __forceinline__ unsigned pack_hi16(unsigned hi_src, unsigned lo_src){
#if defined(__has_builtin)
#if __has_builtin(__builtin_amdgcn_perm)
    return __builtin_amdgcn_perm(hi_src, lo_src, 0x07060302u);
#else
    return (lo_src >> 16) | (hi_src & 0xffff0000u);
#endif
#else
    return (lo_src >> 16) | (hi_src & 0xffff0000u);
#endif
}

union U8 { short8 s; unsigned u[4]; };

#define MFMA16(A,B,C) __builtin_amdgcn_mfma_f32_16x16x32_bf16((A),(B),(C),0,0,0)

// chunk-2 B-frag: slots [x0h,x0l,x0h,x1h,x1l,x1h,1,1] (quad-0 lanes only)
static __device__ __forceinline__ short8 make_b2f(float x0, float x1, bool q0){
    unsigned h0, l0, h1, l1;
    bsplit(x0, h0, l0);
    bsplit(x1, h1, l1);
    U8 B;
    B.u[0] = q0 ? (h0 | (l0 << 16)) : 0u;
    B.u[1] = q0 ? (h0 | (h1 << 16)) : 0u;
    B.u[2] = q0 ? (l1 | (h1 << 16)) : 0u;
    B.u[3] = q0 ? 0x3F803F80u : 0u;
    return B.s;
}

// ---------------------------------------------------------------------------
// Head precompute (verified rounds 1-7): Bhi/Blo bf16 split of
// Bmat[(2r+k)*18+ta][128], Cvec[48].  out[b,r,k] = sum hcat*Bmat + Cvec.
// ---------------------------------------------------------------------------
__global__ __launch_bounds__(256) void head_precompute(
    const float* __restrict__ fc1_w, const float* __restrict__ fc1_b,
    const float* __restrict__ fc2_w, const float* __restrict__ fc2_b,
    unsigned short* __restrict__ Bhi, unsigned short* __restrict__ Blo,
    float* __restrict__ Cvec)
{
    int idx = blockIdx.x * 256 + threadIdx.x;
    if (idx < 24 * 2 * 18 * 128) {
        int jg = idx & 127;
        int t  = (idx >> 7) % 18;
        int k  = (idx / 2304) & 1;
        int r  = idx / 4608;
        float acc = 0.f;
        for (int c = 0; c < 24; ++c) {
            int s = t * 24 + c - r * 18;
            if (s >= 0 && s < 18) acc += fc2_w[k * 18 + s] * fc1_w[c * 128 + jg];
        }
        unsigned hi, lo;
        bsplit(acc, hi, lo);
        Bhi[idx] = (unsigned short)hi;
        Blo[idx] = (unsigned short)lo;
    }
    if (idx < 48) {
        int k = idx & 1, r = idx >> 1;
        float acc = fc2_b[k];
        for (int s = 0; s < 18; ++s)
            acc += fc2_w[k * 18 + s] * fc1_b[(r * 18 + s) % 24];
        Cvec[idx] = acc;
    }
}

// ---------------------------------------------------------------------------
// MFMA GRU: ONE block handles 32 batches, BOTH directions. 512 threads =
// 8 waves: wave = dir*4 + jq (jq = gate column group). Augmented-K,
// log2e-folded weights, W + chunk-2 A-frags persistent in registers.
// h double-buffered per dir in LDS; one barrier per step. Head rotates
// across jq per dir; each dir has its own out_acc plane (no cell races).
// Epilogue: plain stores out = accF + accB + Cvec. No atomics, no memset,
// no register state across barriers, no cross-block communication.
// ---------------------------------------------------------------------------
struct SMv {
    alignas(16) unsigned short hb[2][2][2][2048]; // 32 KiB [parity][dir][hi/lo][(j>>3)*256+b*8+(j&7)]
    float2_t x_s[32][18];                         // 4.5 KiB, read-only after init
    float out_acc[2][32][49];                     // 12.25 KiB [dir][b][cell], stride 49
};

__global__ __launch_bounds__(512, 4) void gru_mfma(
    const float* __restrict__ x,
    const float* __restrict__ w_ih_f, const float* __restrict__ w_hh_f,
    const float* __restrict__ b_ih_f, const float* __restrict__ b_hh_f,
    const float* __restrict__ w_ih_b, const float* __restrict__ w_hh_b,
    const float* __restrict__ b_ih_b, const float* __restrict__ b_hh_b,
    const unsigned short* __restrict__ Bhi, const unsigned short* __restrict__ Blo,
    const float* __restrict__ Cvec, float* __restrict__ out)
{
    __shared__ SMv sm;
    const int tid  = threadIdx.x;
    const int lane = tid & 63;
    const int wave = tid >> 6;
    const int dir  = wave >> 2;
    const int jq   = wave & 3;
    const int col  = lane & 15;
    const int quad = lane >> 4;
    const int bb   = blockIdx.x * 32;
    const bool q0  = (quad == 0);

    const float* __restrict__ wih = dir ? w_ih_b : w_ih_f;
    const float* __restrict__ whh = dir ? w_hh_b : w_hh_f;
    const float* __restrict__ bih = dir ? b_ih_b : b_ih_f;
    const float* __restrict__ bhh = dir ? b_hh_b : b_hh_f;

    const float L1 = 1.4426950408889634f;   // log2(e)
    const float L2 = 2.8853900817779268f;   // 2*log2(e)

    // ---- zero parity-1 h planes (both dirs) and out_acc ----
    {
        unsigned* z = (unsigned*)&sm.hb[1][0][0][0];   // 16 KiB = 4096 uints
        #pragma unroll
        for (int o = 0; o < 8; ++o) z[tid + o * 512] = 0u;
    }
    for (int o = tid; o < 2 * 32 * 49; o += 512) ((float*)sm.out_acc)[o] = 0.f;

    // ---- stage x (read-only after the barrier) ----
    for (int p = tid; p < 32 * 18; p += 512) {
        int b = p / 18, t = p % 18;
        sm.x_s[b][t] = *(const float2_t*)(x + (size_t)(bb + b) * 36 + t * 2);
    }

    // ---- persistent W A-frags (RNE bf16, log2e-scaled): r,z by L1; nh by L2 ----
    short8 wf[3][2];
    #pragma unroll
    for (int ty = 0; ty < 3; ++ty) {
        float sc = (ty == 2) ? L2 : L1;
        int g = ty * 64 + jq * 16 + col;
        #pragma unroll
        for (int c = 0; c < 2; ++c) {
            const float* p = whh + g * 64 + c * 32 + quad * 8;
            float4_t f0 = *(const float4_t*)p;
            float4_t f1 = *(const float4_t*)(p + 4);
            short8 s;
            #pragma unroll
            for (int e = 0; e < 8; ++e) {
                float f = (e < 4) ? f0[e] : f1[e - 4];
                s[e] = (short)(rne_bits(sc * f) >> 16);
            }
            wf[ty][c] = s;
        }
    }

    // ---- chunk-2 A-frags in registers (real data on quad-0 lanes only) ----
    short8 c2[4];
    {
        int g0 = jq * 16 + col;
        #pragma unroll
        for (int ty = 0; ty < 2; ++ty) {      // r, z
            int g = ty * 64 + g0;
            unsigned w0h, w0l, w1h, w1l, bh, bl;
            bsplit(L1 * wih[2 * g],     w0h, w0l);
            bsplit(L1 * wih[2 * g + 1], w1h, w1l);
            bsplit(L1 * (bih[g] + bhh[g]), bh, bl);
            U8 f;
            f.u[0] = q0 ? (w0h | (w0h << 16)) : 0u;
            f.u[1] = q0 ? (w0l | (w1h << 16)) : 0u;
            f.u[2] = q0 ? (w1h | (w1l << 16)) : 0u;
            f.u[3] = q0 ? (bh  | (bl  << 16)) : 0u;
            c2[ty] = f.s;
        }
        {   // nh: h-side bias only
            unsigned bh, bl;
            bsplit(L2 * bhh[128 + g0], bh, bl);
            U8 f;
            f.u[0] = 0u; f.u[1] = 0u; f.u[2] = 0u;
            f.u[3] = q0 ? (bh | (bl << 16)) : 0u;
            c2[2] = f.s;
        }
        {   // nx
            int g = 128 + g0;
            unsigned w0h, w0l, w1h, w1l, bh, bl;
            bsplit(L2 * wih[2 * g],     w0h, w0l);
            bsplit(L2 * wih[2 * g + 1], w1h, w1l);
            bsplit(L2 * bih[g], bh, bl);
            U8 f;
            f.u[0] = q0 ? (w0h | (w0h << 16)) : 0u;
            f.u[1] = q0 ? (w0l | (w1h << 16)) : 0u;
            f.u[2] = q0 ? (w1h | (w1l << 16)) : 0u;
            f.u[3] = q0 ? (bh  | (bl  << 16)) : 0u;
            c2[3] = f.s;
        }
    }

    float hprev[8] = {0.f,0.f,0.f,0.f,0.f,0.f,0.f,0.f};

    __syncthreads();

    auto step = [&](int t, int pr, int pw) {
        const bool myturn = (t > 0) && (((t - 1) & 3) == jq);
        const int tx = dir ? (TT - 1 - t) : t;

        // (1) h-hi B-frags, both N-tiles, this dir's plane
        short8 h0c0 = *(const short8*)&sm.hb[pr][dir][0][quad * 256 + col * 8];
        short8 h0c1 = *(const short8*)&sm.hb[pr][dir][0][(4 + quad) * 256 + col * 8];
        short8 h1c0 = *(const short8*)&sm.hb[pr][dir][0][quad * 256 + (16 + col) * 8];
        short8 h1c1 = *(const short8*)&sm.hb[pr][dir][0][(4 + quad) * 256 + (16 + col) * 8];

        // (2) chunk-2 B-frags from the read-only x stage
        float2_t xv0 = sm.x_s[col][tx];
        float2_t xv1 = sm.x_s[16 + col][tx];
        short8 b2f0 = make_b2f(xv0[0], xv0[1], q0);
        short8 b2f1 = make_b2f(xv1[0], xv1[1], q0);

        // (3) head loads (turn wave only): Bhi/Blo from global + h-lo frags
        short8 hA0, hA1, lA0, lA1, l0c0, l0c1, l1c0, l1c1;
        int base_h = 0;
        if (myturn) {
            int s  = t - 1;
            int ta = dir ? (TT - 1 - s) : s;
            base_h = 4 * (ta / 3) + ta % 3;
            int i  = col & 3;
            int rr = base_h + (i >> 1);
            int kk = i & 1;
            size_t boff = (size_t)((rr * 2 + kk) * TT + ta) * 128 + dir * 64 + quad * 8;
            hA0 = *(const short8*)(Bhi + boff);
            hA1 = *(const short8*)(Bhi + boff + 32);
            lA0 = *(const short8*)(Blo + boff);
            lA1 = *(const short8*)(Blo + boff + 32);
            l0c0 = *(const short8*)&sm.hb[pr][dir][1][quad * 256 + col * 8];
            l0c1 = *(const short8*)&sm.hb[pr][dir][1][(4 + quad) * 256 + col * 8];
            l1c0 = *(const short8*)&sm.hb[pr][dir][1][quad * 256 + (16 + col) * 8];
            l1c1 = *(const short8*)&sm.hb[pr][dir][1][(4 + quad) * 256 + (16 + col) * 8];
        }

        // (4) gate GEMM + elementwise per N-tile; head between the tiles
        #pragma unroll
        for (int nt = 0; nt < 2; ++nt) {
            short8 hc0 = nt ? h1c0 : h0c0;
            short8 hc1 = nt ? h1c1 : h0c1;
            short8 b2f = nt ? b2f1 : b2f0;
            float4_t aR  = (float4_t){0.f,0.f,0.f,0.f};
            float4_t aZ  = (float4_t){0.f,0.f,0.f,0.f};
            float4_t aNH = (float4_t){0.f,0.f,0.f,0.f};
            float4_t aNX = (float4_t){0.f,0.f,0.f,0.f};
            aR  = MFMA16(wf[0][0], hc0, aR);
            aR  = MFMA16(wf[0][1], hc1, aR);
            aR  = MFMA16(c2[0],    b2f, aR);
            aZ  = MFMA16(wf[1][0], hc0, aZ);
            aZ  = MFMA16(wf[1][1], hc1, aZ);
            aZ  = MFMA16(c2[1],    b2f, aZ);
            aNH = MFMA16(wf[2][0], hc0, aNH);
            aNH = MFMA16(wf[2][1], hc1, aNH);
            aNH = MFMA16(c2[2],    b2f, aNH);
            aNX = MFMA16(c2[3],    b2f, aNX);

            unsigned rh[4], rl[4];
            #pragma unroll
            for (int reg = 0; reg < 4; ++reg) {
                float r = frcp(1.f + FEXP2(-aR[reg]));
                float z = frcp(1.f + FEXP2(-aZ[reg]));
                float a = fmaf(r, aNH[reg], aNX[reg]);
                float n = fmaf(2.f, frcp(1.f + FEXP2(-a)), -1.f);
                float hnew = fmaf(z, hprev[nt * 4 + reg] - n, n);
                hprev[nt * 4 + reg] = hnew;
                unsigned rb = rne_bits(hnew);
                rh[reg] = rb;
                rl[reg] = __float_as_uint(hnew - __uint_as_float(rb & 0xffff0000u));
            }
            int woff = (jq * 2 + (quad >> 1)) * 256 + (nt * 16 + col) * 8 + (quad & 1) * 4;
            uint2_t dh, dl;
            dh[0] = pack_hi16(rh[1], rh[0]);
            dh[1] = pack_hi16(rh[3], rh[2]);
            dl[0] = pack_hi16(rl[1], rl[0]);
            dl[1] = pack_hi16(rl[3], rl[2]);
            *(uint2_t*)&sm.hb[pw][dir][0][woff] = dh;
            *(uint2_t*)&sm.hb[pw][dir][1][woff] = dl;

            if (nt == 0 && myturn) {
                float4_t a0 = (float4_t){0.f,0.f,0.f,0.f};
                a0 = MFMA16(hA0, h0c0, a0);
                a0 = MFMA16(hA1, h0c1, a0);
                a0 = MFMA16(hA0, l0c0, a0);
                a0 = MFMA16(hA1, l0c1, a0);
                a0 = MFMA16(lA0, h0c0, a0);
                a0 = MFMA16(lA1, h0c1, a0);
                float4_t a1 = (float4_t){0.f,0.f,0.f,0.f};
                a1 = MFMA16(hA0, h1c0, a1);
                a1 = MFMA16(hA1, h1c1, a1);
                a1 = MFMA16(hA0, l1c0, a1);
                a1 = MFMA16(hA1, l1c1, a1);
                a1 = MFMA16(lA0, h1c0, a1);
                a1 = MFMA16(lA1, h1c1, a1);
                if (q0) {
                    #pragma unroll
                    for (int reg = 0; reg < 4; ++reg) {
                        int cell = (base_h + (reg >> 1)) * 2 + (reg & 1);
                        sm.out_acc[dir][col][cell]      += a0[reg];
                        sm.out_acc[dir][16 + col][cell] += a1[reg];
                    }
                }
            }
        }

        __syncthreads();
    };

    #pragma unroll 1
    for (int tt = 0; tt < 9; ++tt) {
        step(2 * tt,     1, 0);
        step(2 * tt + 1, 0, 1);
    }

    // ---- final head for s = 17 (h17 in parity 1), jq == 1 waves of each dir ----
    if (jq == ((TT - 1) & 3)) {
        int s  = TT - 1;
        int ta = dir ? 0 : s;
        int base_h = 4 * (ta / 3) + ta % 3;
        int i  = col & 3;
        int rr = base_h + (i >> 1);
        int kk = i & 1;
        size_t boff = (size_t)((rr * 2 + kk) * TT + ta) * 128 + dir * 64 + quad * 8;
        short8 hA0 = *(const short8*)(Bhi + boff);
        short8 hA1 = *(const short8*)(Bhi + boff + 32);
        short8 lA0 = *(const short8*)(Blo + boff);
        short8 lA1 = *(const short8*)(Blo + boff + 32);
        #pragma unroll
        for (int nt = 0; nt < 2; ++nt) {
            short8 hc0 = *(const short8*)&sm.hb[1][dir][0][quad * 256 + (nt * 16 + col) * 8];
            short8 hc1 = *(const short8*)&sm.hb[1][dir][0][(4 + quad) * 256 + (nt * 16 + col) * 8];
            short8 lc0 = *(const short8*)&sm.hb[1][dir][1][quad * 256 + (nt * 16 + col) * 8];
            short8 lc1 = *(const short8*)&sm.hb[1][dir][1][(4 + quad) * 256 + (nt * 16 + col) * 8];
            float4_t acch = (float4_t){0.f,0.f,0.f,0.f};
            acch = MFMA16(hA0, hc0, acch);
            acch = MFMA16(hA1, hc1, acch);
            acch = MFMA16(hA0, lc0, acch);
            acch = MFMA16(hA1, lc1, acch);
            acch = MFMA16(lA0, hc0, acch);
            acch = MFMA16(lA1, hc1, acch);
            if (q0) {
                #pragma unroll
                for (int reg = 0; reg < 4; ++reg) {
                    int cell = (base_h + (reg >> 1)) * 2 + (reg & 1);
                    sm.out_acc[dir][nt * 16 + col][cell] += acch[reg];
                }
            }
        }
    }
    __syncthreads();

    // ---- epilogue: deterministic plain stores, both dirs summed in fixed order ----
    #pragma unroll
    for (int rep = 0; rep < 3; ++rep) {
        int o = rep * 512 + tid;          // 1536 = 32 b * 48 cells
        int b = o / 48, c = o % 48;
        out[(size_t)bb * 48 + o] = sm.out_acc[0][b][c] + sm.out_acc[1][b][c] + Cvec[c];
    }
}

extern "C" void kernel_launch(void* const* d_in, const int* in_sizes, int n_in,
                              void* d_out, int out_size, void* d_ws, size_t ws_size,
                              hipStream_t stream) {
    const float* x      = (const float*)d_in[0];
    const float* w_ih_f = (const float*)d_in[1];
    const float* w_hh_f = (const float*)d_in[2];
    const float* b_ih_f = (const float*)d_in[3];
    const float* b_hh_f = (const float*)d_in[4];
    const float* w_ih_b = (const float*)d_in[5];
    const float* w_hh_b = (const float*)d_in[6];
    const float* b_ih_b = (const float*)d_in[7];
    const float* b_hh_b = (const float*)d_in[8];
    const float* fc1_w  = (const float*)d_in[9];
    const float* fc1_b  = (const float*)d_in[10];
    const float* fc2_w  = (const float*)d_in[11];
    const float* fc2_b  = (const float*)d_in[12];
    float* out  = (float*)d_out;

    float*          Cvec = (float*)d_ws;                          // 48 floats (+pad)
    unsigned short* Bhi  = (unsigned short*)((char*)d_ws + 256);  // 110592 ushorts
    unsigned short* Blo  = Bhi + 110592;                          // 110592 ushorts

    head_precompute<<<432, 256, 0, stream>>>(fc1_w, fc1_b, fc2_w, fc2_b, Bhi, Blo, Cvec);
    gru_mfma<<<1024, 512, 0, stream>>>(x, w_ih_f, w_hh_f, b_ih_f, b_hh_f,
                                       w_ih_b, w_hh_b, b_ih_b, b_hh_b,
                                       Bhi, Blo, Cvec, out);
}